// Round 3
// baseline (2218.087 us; speedup 1.0000x reference)
//
#include <hip/hip_runtime.h>

#define BB 4
#define NN 16384
#define CC 64
#define NPOINT 1024
#define NSAMPLE 32

#define FPS_T 1024
#define NCHUNK 256          // 64 points per chunk
#define NCELL 4096          // 16^3 Morton cells

#define REPEAT16(M) M(0) M(1) M(2) M(3) M(4) M(5) M(6) M(7) \
                    M(8) M(9) M(10) M(11) M(12) M(13) M(14) M(15)
// (k, tb-pair index, hi-half?)
#define REPEAT16P(M) M(0,0,0) M(1,0,1) M(2,1,0) M(3,1,1) \
                     M(4,2,0) M(5,2,1) M(6,3,0) M(7,3,1) \
                     M(8,4,0) M(9,4,1) M(10,5,0) M(11,5,1) \
                     M(12,6,0) M(13,6,1) M(14,7,0) M(15,7,1)

// ---------------------------------------------------------------------------
// K1: Pruned FPS, 16 waves, event-driven reductions, atomic cross-wave
// reduce, no global/LDS ops in the UPD hot path.
//  - amdgpu_waves_per_eu(4,4): LDS no longer caps occupancy, but a 1024-thr
//    block = 16 waves = 4 waves/EU when resident alone; pinning the range
//    gives the allocator the full 512/4 = 128-VGPR budget. (launch_bounds'
//    2nd arg was IGNORED by hipcc: R2 showed identical 64-VGPR code.)
//  - Live set ~90: x/y/z/d x16 = 64, tb packed 2x14b per u32 = 8, AABB 6,
//    loop state ~12. Fits 128 with headroom -> no scratch.
//  - sxy LDS array REMOVED (dead since x/y went to registers): holder
//    coords come from register selects. LDS now 17 KiB.
//  - Morton counting-sort to global sb (float4 x,y,z,orig).
//  - Wave wv owns chunks {wv+16k}; lane L holds point L of each chunk in
//    registers (asm-pinned). AABB of chunk wv+16k in lane-k registers.
//  - Prune: chunk active iff mind2(AABB,c) <= min(prev_wd, cub)*1.001 where
//    cub = min over processed centroids of maxdist2(AABB,c) >= chunk max d.
//  - Event-driven: lane best (bd,btb) recomputed only when its best chunk's
//    d decreased; wave butterfly only when holder lane's best decreased.
//    (d,tb) lexicographic max == u64 key max; tb unique -> exact ties.
//  - Cross-wave: holder writes coords to wbc dbuf + ONE atomicMax of
//    (key|wv) into slot[it&3]; ONE barrier; slot read and wbc[lane] read
//    issue in parallel; winner id via readfirstlane, coords via v_readlane
//    (pure VALU -- replaces 3 serial ds_bpermute shfls).
//  - Centroids buffered in LDS outc[], flushed after the loop.
// Bit-exact: contract(off), (dx*dx+dy*dy)+dz*dz order, min-as-cond-update.
// ---------------------------------------------------------------------------
__global__
__attribute__((amdgpu_flat_work_group_size(FPS_T, FPS_T)))
__attribute__((amdgpu_waves_per_eu(4, 4)))
void fps_kernel(const float* __restrict__ xyz,
                float* __restrict__ new_xyz,
                float4* __restrict__ sorted) {
    #pragma clang fp contract(off)
    extern __shared__ char smem_raw[];
    int*    hist = (int*)smem_raw;                            // 16384 B (setup)
    float*  outc = (float*)smem_raw;                          // 12288 B (alias)
    float4* wbc  = (float4*)(smem_raw + 16384);               // [2][16] 512 B
    unsigned long long* slot = (unsigned long long*)(smem_raw + 16896); // [4]
    int*    wsum = (int*)(smem_raw + 16928);                  // [16]

    const int b    = blockIdx.x;
    const int tid  = threadIdx.x;
    const int lane = tid & 63;
    const int wv   = tid >> 6;                  // 0..15
    const float* bx = xyz + (size_t)b * NN * 3;
    float4* sb = sorted + (size_t)b * NN;

    // ---------- phase 0a: histogram of Morton cell codes ----------
    #pragma unroll
    for (int j = 0; j < 4; ++j) hist[j * FPS_T + tid] = 0;
    __syncthreads();

    #pragma unroll
    for (int j = 0; j < 16; ++j) {
        const int p = j * FPS_T + tid;
        const float x = bx[p * 3 + 0], y = bx[p * 3 + 1], z = bx[p * 3 + 2];
        int cx = (int)(x * 16.0f); cx = cx > 15 ? 15 : (cx < 0 ? 0 : cx);
        int cy = (int)(y * 16.0f); cy = cy > 15 ? 15 : (cy < 0 ? 0 : cy);
        int cz = (int)(z * 16.0f); cz = cz > 15 ? 15 : (cz < 0 ? 0 : cz);
        int code = 0;
        #pragma unroll
        for (int i = 0; i < 4; ++i)
            code |= (((cx >> i) & 1) << (3 * i)) |
                    (((cy >> i) & 1) << (3 * i + 1)) |
                    (((cz >> i) & 1) << (3 * i + 2));
        atomicAdd(&hist[code], 1);
    }
    __syncthreads();

    // ---------- phase 0b: exclusive scan ----------
    {
        const int h0 = hist[4 * tid + 0], h1 = hist[4 * tid + 1];
        const int h2 = hist[4 * tid + 2], h3 = hist[4 * tid + 3];
        const int s  = h0 + h1 + h2 + h3;
        int v = s;
        #pragma unroll
        for (int o = 1; o < 64; o <<= 1) {
            const int u = __shfl_up(v, o, 64);
            if (lane >= o) v += u;
        }
        if (lane == 63) wsum[wv] = v;
        __syncthreads();
        int base = 0;
        for (int w = 0; w < wv; ++w) base += wsum[w];
        const int e0 = base + v - s;
        hist[4 * tid + 0] = e0;
        hist[4 * tid + 1] = e0 + h0;
        hist[4 * tid + 2] = e0 + h0 + h1;
        hist[4 * tid + 3] = e0 + h0 + h1 + h2;
    }
    __syncthreads();

    // ---------- phase 0c: scatter to global sb ----------
    #pragma unroll
    for (int j = 0; j < 16; ++j) {
        const int p = j * FPS_T + tid;
        const float x = bx[p * 3 + 0], y = bx[p * 3 + 1], z = bx[p * 3 + 2];
        int cx = (int)(x * 16.0f); cx = cx > 15 ? 15 : (cx < 0 ? 0 : cx);
        int cy = (int)(y * 16.0f); cy = cy > 15 ? 15 : (cy < 0 ? 0 : cy);
        int cz = (int)(z * 16.0f); cz = cz > 15 ? 15 : (cz < 0 ? 0 : cz);
        int code = 0;
        #pragma unroll
        for (int i = 0; i < 4; ++i)
            code |= (((cx >> i) & 1) << (3 * i)) |
                    (((cy >> i) & 1) << (3 * i + 1)) |
                    (((cz >> i) & 1) << (3 * i + 2));
        const int slotg = atomicAdd(&hist[code], 1);
        sb[slotg] = make_float4(x, y, z, __int_as_float(p));
    }
    __syncthreads();   // drains scatter stores before readback

    // ---------- phase 0d: per-chunk coords/tb preload + AABB ----------
#define DECLP(k) float x##k, y##k, z##k, d##k;
    REPEAT16(DECLP)
#undef DECLP
    unsigned tbp0, tbp1, tbp2, tbp3, tbp4, tbp5, tbp6, tbp7;
    float abx0 = 0.f, aby0 = 0.f, abz0 = 0.f, abx1 = 0.f, aby1 = 0.f, abz1 = 0.f;

#define AABBPRE(k, pr, hi) { const int g = wv + ((k) << 4);               \
    const float4 pt = sb[(g << 6) + lane];                                \
    x##k = pt.x; y##k = pt.y; z##k = pt.z;                                \
    d##k = 1e10f;                                                         \
    const unsigned tb = 0x3FFFu - (unsigned)__float_as_int(pt.w);         \
    if (hi) tbp##pr |= (tb << 16); else tbp##pr = tb;                     \
    float mnx = pt.x, mxx = pt.x, mny = pt.y, mxy = pt.y,                 \
          mnz = pt.z, mxz = pt.z;                                         \
    _Pragma("unroll")                                                     \
    for (int m = 32; m >= 1; m >>= 1) {                                   \
        mnx = fminf(mnx, __shfl_xor(mnx, m, 64));                         \
        mxx = fmaxf(mxx, __shfl_xor(mxx, m, 64));                         \
        mny = fminf(mny, __shfl_xor(mny, m, 64));                         \
        mxy = fmaxf(mxy, __shfl_xor(mxy, m, 64));                         \
        mnz = fminf(mnz, __shfl_xor(mnz, m, 64));                         \
        mxz = fmaxf(mxz, __shfl_xor(mxz, m, 64));                         \
    }                                                                     \
    if (lane == (k)) { abx0 = mnx; abx1 = mxx; aby0 = mny; aby1 = mxy;    \
                       abz0 = mnz; abz1 = mxz; } }
    REPEAT16P(AABBPRE)
#undef AABBPRE
    if (tid == 0) { slot[0] = 0ull; slot[1] = 0ull; slot[2] = 0ull; slot[3] = 0ull; }
    __syncthreads();

    // ---------- main loop ----------
    float bd = 0.0f;                  // my lane best distance
    unsigned btb = 0u;                // my lane best tie-break
    int bestk = 0;
    int holder_ln = 0;                // wave-uniform
    unsigned long long hkey = 0ull;   // wave-uniform: holder's key
    float hx = 0.f, hy = 0.f, hz = 0.f;
    float cub = 1e10f;                // lane k: upper bound on chunk max d

    float ccx = bx[0], ccy = bx[1], ccz = bx[2];
    float prev_wd = 1e10f;

    for (int it = 0; it < NPOINT; ++it) {
        asm volatile("" : "+v"(x0), "+v"(x1), "+v"(x2),  "+v"(x3),
                          "+v"(x4), "+v"(x5), "+v"(x6),  "+v"(x7),
                          "+v"(x8), "+v"(x9), "+v"(x10), "+v"(x11),
                          "+v"(x12), "+v"(x13), "+v"(x14), "+v"(x15));
        asm volatile("" : "+v"(y0), "+v"(y1), "+v"(y2),  "+v"(y3),
                          "+v"(y4), "+v"(y5), "+v"(y6),  "+v"(y7),
                          "+v"(y8), "+v"(y9), "+v"(y10), "+v"(y11),
                          "+v"(y12), "+v"(y13), "+v"(y14), "+v"(y15));
        asm volatile("" : "+v"(z0), "+v"(z1), "+v"(z2),  "+v"(z3),
                          "+v"(z4), "+v"(z5), "+v"(z6),  "+v"(z7),
                          "+v"(z8), "+v"(z9), "+v"(z10), "+v"(z11),
                          "+v"(z12), "+v"(z13), "+v"(z14), "+v"(z15));
        asm volatile("" : "+v"(d0), "+v"(d1), "+v"(d2),  "+v"(d3),
                          "+v"(d4), "+v"(d5), "+v"(d6),  "+v"(d7),
                          "+v"(d8), "+v"(d9), "+v"(d10), "+v"(d11),
                          "+v"(d12), "+v"(d13), "+v"(d14), "+v"(d15));

        if (tid == 0) {
            outc[it * 3 + 0] = ccx;
            outc[it * 3 + 1] = ccy;
            outc[it * 3 + 2] = ccz;
        }

        // --- AABB prune + cub maintenance (lane k -> chunk wv+16k) ---
        bool active = false;
        if (lane < 16) {
            const float dxl = fmaxf(fmaxf(abx0 - ccx, ccx - abx1), 0.0f);
            const float dyl = fmaxf(fmaxf(aby0 - ccy, ccy - aby1), 0.0f);
            const float dzl = fmaxf(fmaxf(abz0 - ccz, ccz - abz1), 0.0f);
            const float mind2 = dxl * dxl + dyl * dyl + dzl * dzl;
            const float bound = fminf(prev_wd, cub);
            active = !(mind2 > bound * 1.001f);
            if (active) {
                // chunk will be processed with this centroid: tighten cub
                const float dxm = fmaxf(ccx - abx0, abx1 - ccx);
                const float dym = fmaxf(ccy - aby0, aby1 - ccy);
                const float dzm = fmaxf(ccz - abz0, abz1 - ccz);
                const float maxd2 = dxm * dxm + dym * dym + dzm * dzm;
                cub = fminf(cub, maxd2);
            }
        }
        const unsigned amask = (unsigned)(__ballot(active) & 0xFFFFull);

        bool lredo = false;
#define UPD(k) if (amask & (1u << (k))) {                                 \
            const float dx = x##k - ccx;                                  \
            const float dy = y##k - ccy;                                  \
            const float dz = z##k - ccz;                                  \
            const float t  = (dx * dx + dy * dy) + dz * dz;               \
            if (t < d##k) {                                               \
                d##k = t;                                                 \
                lredo |= ((k) == bestk);                                  \
            }                                                             \
        }
        if (amask & 0x000Fu) { UPD(0)  UPD(1)  UPD(2)  UPD(3)  }
        if (amask & 0x00F0u) { UPD(4)  UPD(5)  UPD(6)  UPD(7)  }
        if (amask & 0x0F00u) { UPD(8)  UPD(9)  UPD(10) UPD(11) }
        if (amask & 0xF000u) { UPD(12) UPD(13) UPD(14) UPD(15) }
#undef UPD

        // --- per-lane best: recompute only when invalidated ---
        // (d,tb) lexicographic max == u64 key max (unique tb -> no ties)
        if (lredo) {
            bd = 0.0f; btb = 0u; bestk = 0;
#define LM(k, pr, hi) { const unsigned tbk = (hi) ? (tbp##pr >> 16)       \
                                                  : (tbp##pr & 0xFFFFu);  \
                        if (d##k > bd || (d##k == bd && tbk > btb)) {     \
                            bd = d##k; btb = tbk; bestk = (k); } }
            REPEAT16P(LM)
#undef LM
        }

        // --- wave best: butterfly only when holder's best decreased ---
        const unsigned long long rb = __ballot(lredo);
        if ((rb >> holder_ln) & 1ull) {
            const unsigned long long bkeyv =
                (((unsigned long long)__float_as_uint(bd)) << 32) |
                ((unsigned long long)btb << 4);
            unsigned long long m = bkeyv;
            #pragma unroll
            for (int s = 32; s >= 1; s >>= 1) {
                const unsigned long long o = __shfl_xor(m, s, 64);
                m = o > m ? o : m;
            }
            holder_ln = __ffsll((long long)__ballot(bkeyv == m)) - 1;  // unique
            hkey = m;
            if (lane == holder_ln) {
#define ZS(k) if (bestk == (k)) { hx = x##k; hy = y##k; hz = z##k; }
                REPEAT16(ZS)
#undef ZS
            }
        }

        // --- cross-wave: coords write + ONE atomicMax; ONE barrier ---
        if (lane == holder_ln) {
            wbc[(it & 1) * 16 + wv] = make_float4(hx, hy, hz, 0.0f);
            atomicMax(&slot[it & 3], hkey | (unsigned long long)wv);
        }
        if (tid == 0) slot[(it + 1) & 3] = 0ull;
        __syncthreads();

        // --- winner: slot read and wbc[lane] read issue in parallel; ---
        // --- coords via v_readlane off readfirstlane'd winner id      ---
        const unsigned long long wk = slot[it & 3];
        float cwx = 0.f, cwy = 0.f, cwz = 0.f;
        if (lane < 16) {
            const float4 wf = wbc[(it & 1) * 16 + lane];
            cwx = wf.x; cwy = wf.y; cwz = wf.z;
        }
        prev_wd = __uint_as_float(
            (unsigned)__builtin_amdgcn_readfirstlane((int)(unsigned)(wk >> 32)));
        const int wwv = __builtin_amdgcn_readfirstlane((int)((unsigned)wk & 0xFu));
        ccx = __int_as_float(__builtin_amdgcn_readlane(__float_as_int(cwx), wwv));
        ccy = __int_as_float(__builtin_amdgcn_readlane(__float_as_int(cwy), wwv));
        ccz = __int_as_float(__builtin_amdgcn_readlane(__float_as_int(cwz), wwv));
    }

    // ---------- flush centroids ----------
    __syncthreads();
    float* outb = new_xyz + (size_t)b * NPOINT * 3;
    #pragma unroll
    for (int j = 0; j < 3; ++j) {
        const int idx = j * FPS_T + tid;
        outb[idx] = outc[idx];
    }
}

// ---------------------------------------------------------------------------
// K2: Ball query. One wave per query; ordered first-32 selection via ballot,
// early exit once 32 found. Exact arithmetic (contract off, rad2 = (float)0.04).
// ---------------------------------------------------------------------------
__global__ __launch_bounds__(256) void ballq_kernel(const float* __restrict__ xyz,
                                                    const float* __restrict__ new_xyz,
                                                    int* __restrict__ gidx) {
    #pragma clang fp contract(off)
    const int lane = threadIdx.x & 63;
    const int q    = blockIdx.x * 4 + (threadIdx.x >> 6);
    const int b    = q >> 10;                  // NPOINT = 1024
    const float* bx = xyz + (size_t)b * NN * 3;
    const float* nx = new_xyz + (size_t)q * 3;
    const float cx = nx[0], cy = nx[1], cz = nx[2];
    const float rad2 = 0.04f;  // f32 cast of python double 0.2**2 — NOT 0.2f*0.2f

    int* out  = gidx + (size_t)q * NSAMPLE;
    int taken = 0;
    int first = NN - 1;

    for (int chunk = 0; chunk < NN / 64 && taken < NSAMPLE; ++chunk) {
        const int   i  = chunk * 64 + lane;
        const float dx = cx - bx[i * 3 + 0];
        const float dy = cy - bx[i * 3 + 1];
        const float dz = cz - bx[i * 3 + 2];
        const float t  = dx * dx + dy * dy + dz * dz;
        const bool ok  = !(t > rad2);
        const unsigned long long m = __ballot(ok);
        const int cnt = __popcll(m);
        if (taken == 0 && cnt > 0) first = chunk * 64 + (__ffsll((long long)m) - 1);
        if (ok) {
            const int rank = taken + __popcll(m & ((1ull << lane) - 1ull));
            if (rank < NSAMPLE) out[rank] = i;
        }
        taken += cnt;
    }
    const int sat = taken < NSAMPLE ? taken : NSAMPLE;
    if (lane >= sat && lane < NSAMPLE) out[lane] = (taken > 0) ? first : (NN - 1);
}

// ---------------------------------------------------------------------------
// K3: gather feats -> LDS, MLP1 (67->64) + relu, MLP2 (64->128) + relu,
// max over the 32 samples. One 256-thread block per query. FMA allowed.
// ---------------------------------------------------------------------------
__global__ __launch_bounds__(256) void mlp_kernel(const float* __restrict__ xyz,
                                                  const float* __restrict__ points,
                                                  const float* __restrict__ w1,
                                                  const float* __restrict__ b1,
                                                  const float* __restrict__ w2,
                                                  const float* __restrict__ b2,
                                                  const float* __restrict__ new_xyz,
                                                  const int*   __restrict__ gidx,
                                                  float* __restrict__ new_points) {
    __shared__ __align__(16) float feats[32][68];
    __shared__ __align__(16) float h1s[32][64];
    __shared__ float pmax[2][128];

    const int q = blockIdx.x;
    const int b = q >> 10;
    const int t = threadIdx.x;

    {
        const int k  = t >> 3;
        const int l8 = t & 7;
        const int gi = gidx[q * 32 + k];
        const float* prow = points + ((size_t)b * NN + gi) * CC;
        const float4 v0 = *(const float4*)(prow + l8 * 8);
        const float4 v1 = *(const float4*)(prow + l8 * 8 + 4);
        *(float4*)&feats[k][4 + l8 * 8] = v0;
        *(float4*)&feats[k][8 + l8 * 8] = v1;
        if (l8 == 0) {
            const float* pr = xyz + ((size_t)b * NN + gi) * 3;
            const float* nr = new_xyz + (size_t)q * 3;
            feats[k][0] = pr[0] - nr[0];
            feats[k][1] = pr[1] - nr[1];
            feats[k][2] = pr[2] - nr[2];
        }
    }

    const int c1 = t & 63;
    float w1r[67];
    #pragma unroll
    for (int j = 0; j < 67; ++j) w1r[j] = w1[c1 * 67 + j];
    const float bb1 = b1[c1];
    __syncthreads();

    const int kg = t >> 6;
    #pragma unroll
    for (int kk = 0; kk < 8; ++kk) {
        const int kr = kg * 8 + kk;
        float acc = bb1;
        acc += feats[kr][0] * w1r[0] + feats[kr][1] * w1r[1] + feats[kr][2] * w1r[2];
        #pragma unroll
        for (int j = 0; j < 64; j += 4) {
            const float4 f = *(const float4*)&feats[kr][4 + j];
            acc += f.x * w1r[3 + j] + f.y * w1r[4 + j] + f.z * w1r[5 + j] + f.w * w1r[6 + j];
        }
        h1s[kr][c1] = fmaxf(acc, 0.0f);
    }

    const int o2 = t & 127;
    const int kh = t >> 7;
    float w2r[64];
    #pragma unroll
    for (int j = 0; j < 64; ++j) w2r[j] = w2[o2 * 64 + j];
    const float bb2 = b2[o2];
    __syncthreads();

    float mx = -INFINITY;
    #pragma unroll
    for (int kk = 0; kk < 16; ++kk) {
        const int kr = kh * 16 + kk;
        float acc = bb2;
        #pragma unroll
        for (int j = 0; j < 64; j += 4) {
            const float4 h = *(const float4*)&h1s[kr][j];
            acc += h.x * w2r[j] + h.y * w2r[j + 1] + h.z * w2r[j + 2] + h.w * w2r[j + 3];
        }
        mx = fmaxf(mx, fmaxf(acc, 0.0f));
    }
    pmax[kh][o2] = mx;
    __syncthreads();
    if (t < 128) {
        new_points[(size_t)q * 128 + t] = fmaxf(pmax[0][t], pmax[1][t]);
    }
}

// ---------------------------------------------------------------------------
extern "C" void kernel_launch(void* const* d_in, const int* in_sizes, int n_in,
                              void* d_out, int out_size, void* d_ws, size_t ws_size,
                              hipStream_t stream) {
    const float* xyz    = (const float*)d_in[0];
    const float* points = (const float*)d_in[1];
    const float* w1     = (const float*)d_in[2];
    const float* b1     = (const float*)d_in[3];
    const float* w2     = (const float*)d_in[4];
    const float* b2     = (const float*)d_in[5];

    float* out_newxyz    = (float*)d_out;
    float* out_newpoints = (float*)d_out + (size_t)BB * NPOINT * 3;
    int*    gidx    = (int*)d_ws;                                   // 512 KB
    float4* sortbuf = (float4*)((char*)d_ws + (size_t)512 * 1024);  // 1 MB

    // LDS map: hist/outc alias @0 (16384) | wbc @16384 (512) |
    // slot @16896 (32) | wsum @16928 (64)  -> total 16992 B
    const int fps_lds = 16992;

    fps_kernel<<<BB, FPS_T, fps_lds, stream>>>(xyz, out_newxyz, sortbuf);
    ballq_kernel<<<(BB * NPOINT) / 4, 256, 0, stream>>>(xyz, out_newxyz, gidx);
    mlp_kernel<<<BB * NPOINT, 256, 0, stream>>>(xyz, points, w1, b1, w2, b2,
                                                out_newxyz, gidx, out_newpoints);
}

// Round 4
// 1731.284 us; speedup vs baseline: 1.2812x; 1.2812x over previous
//
#include <hip/hip_runtime.h>

#define BB 4
#define NN 16384
#define CC 64
#define NPOINT 1024
#define NSAMPLE 32

#define FPS_T 1024
#define NCHUNK 256          // 64 points per chunk
#define NCELL 4096          // 16^3 Morton cells

#define REPEAT16(M) M(0) M(1) M(2) M(3) M(4) M(5) M(6) M(7) \
                    M(8) M(9) M(10) M(11) M(12) M(13) M(14) M(15)

// ---------------------------------------------------------------------------
// K1: Pruned FPS, 16 waves, event-driven reductions, atomic cross-wave
// reduce. DESIGNED FOR THE 64-VGPR BUDGET the compiler actually grants
// (R2/R3 showed launch_bounds/waves_per_eu attrs do NOT raise it; spills
// to scratch cost ~40% — so live set is kept ~15 regs BELOW R0's 56):
//  - z##k + d##k in regs (32). u64 keys REPLACED by f32 d (saves 16 regs,
//    cheapens UPD/LM). tb (tie-break, 0x3FFF-orig, globally unique) loaded
//    ON DEMAND from sb.w (global, L2-resident) only on the rare lredo path.
//  - sxy2 LDS layout [wv][k][lane] (float2): a wave's 16 chunks sit at
//    stride 64 float2, so a nibble's 4 loads batch (independent
//    ds_read_b64, conflict-free, mergeable to ds_read2st64_b64) instead of
//    R0's one-branch-one-load 120cy serial chain.
//  - UPD is unconditional within an active nibble (min-update is exact for
//    any chunk; prune only decides SKIPPING). cub tightening gated on
//    nibble-processed -- still a valid upper bound (update really ran).
//  - Event-driven: lane best recomputed only when its best chunk's d
//    decreased; wave reduce only when holder's best decreased. Wave reduce
//    = f32 butterfly (6 single-b32 swizzles) + ballot; exact u64-key
//    butterfly fallback only on cross-lane d-ties. Holder builds the
//    atomic key from its OWN (bd,btb) -- no broadcast.
//  - Cross-wave: holder writes coords to wbc dbuf + ONE atomicMax of
//    (d<<32|tb<<4|wv) into slot[it&3]; ONE barrier; slot read and
//    wbc[lane] read issue in parallel; winner id via readfirstlane,
//    coords via v_readlane (no dependent LDS chain).
//  - Centroids buffered in LDS outc[], flushed after the loop.
// Bit-exact: contract(off), (dx*dx+dy*dy)+dz*dz order, min-as-cond-update,
// ties resolved to smallest original index at lane/wave/block level.
// ---------------------------------------------------------------------------
__global__ __launch_bounds__(FPS_T) void fps_kernel(const float* __restrict__ xyz,
                                                    float* __restrict__ new_xyz,
                                                    float4* __restrict__ sorted) {
    #pragma clang fp contract(off)
    extern __shared__ char smem_raw[];
    float2* sxy2 = (float2*)smem_raw;                         // 131072 B [wv][k][lane]
    int*    hist = (int*)(smem_raw + 131072);                 // 16384 B (setup)
    float*  outc = (float*)(smem_raw + 131072);               // 12288 B (alias)
    float4* wbc  = (float4*)(smem_raw + 147456);              // [2][16] 512 B
    unsigned long long* slot = (unsigned long long*)(smem_raw + 147968); // [4]
    int*    wsum = (int*)(smem_raw + 148000);                 // [16]

    const int b    = blockIdx.x;
    const int tid  = threadIdx.x;
    const int lane = tid & 63;
    const int wv   = tid >> 6;                  // 0..15
    const float* bx = xyz + (size_t)b * NN * 3;
    float4* sb = sorted + (size_t)b * NN;

    // ---------- phase 0a: histogram of Morton cell codes ----------
    #pragma unroll
    for (int j = 0; j < 4; ++j) hist[j * FPS_T + tid] = 0;
    __syncthreads();

    #pragma unroll
    for (int j = 0; j < 16; ++j) {
        const int p = j * FPS_T + tid;
        const float x = bx[p * 3 + 0], y = bx[p * 3 + 1], z = bx[p * 3 + 2];
        int cx = (int)(x * 16.0f); cx = cx > 15 ? 15 : (cx < 0 ? 0 : cx);
        int cy = (int)(y * 16.0f); cy = cy > 15 ? 15 : (cy < 0 ? 0 : cy);
        int cz = (int)(z * 16.0f); cz = cz > 15 ? 15 : (cz < 0 ? 0 : cz);
        int code = 0;
        #pragma unroll
        for (int i = 0; i < 4; ++i)
            code |= (((cx >> i) & 1) << (3 * i)) |
                    (((cy >> i) & 1) << (3 * i + 1)) |
                    (((cz >> i) & 1) << (3 * i + 2));
        atomicAdd(&hist[code], 1);
    }
    __syncthreads();

    // ---------- phase 0b: exclusive scan ----------
    {
        const int h0 = hist[4 * tid + 0], h1 = hist[4 * tid + 1];
        const int h2 = hist[4 * tid + 2], h3 = hist[4 * tid + 3];
        const int s  = h0 + h1 + h2 + h3;
        int v = s;
        #pragma unroll
        for (int o = 1; o < 64; o <<= 1) {
            const int u = __shfl_up(v, o, 64);
            if (lane >= o) v += u;
        }
        if (lane == 63) wsum[wv] = v;
        __syncthreads();
        int base = 0;
        for (int w = 0; w < wv; ++w) base += wsum[w];
        const int e0 = base + v - s;
        hist[4 * tid + 0] = e0;
        hist[4 * tid + 1] = e0 + h0;
        hist[4 * tid + 2] = e0 + h0 + h1;
        hist[4 * tid + 3] = e0 + h0 + h1 + h2;
    }
    __syncthreads();

    // ---------- phase 0c: scatter to global sb AND LDS sxy2 (permuted) ----------
    #pragma unroll
    for (int j = 0; j < 16; ++j) {
        const int p = j * FPS_T + tid;
        const float x = bx[p * 3 + 0], y = bx[p * 3 + 1], z = bx[p * 3 + 2];
        int cx = (int)(x * 16.0f); cx = cx > 15 ? 15 : (cx < 0 ? 0 : cx);
        int cy = (int)(y * 16.0f); cy = cy > 15 ? 15 : (cy < 0 ? 0 : cy);
        int cz = (int)(z * 16.0f); cz = cz > 15 ? 15 : (cz < 0 ? 0 : cz);
        int code = 0;
        #pragma unroll
        for (int i = 0; i < 4; ++i)
            code |= (((cx >> i) & 1) << (3 * i)) |
                    (((cy >> i) & 1) << (3 * i + 1)) |
                    (((cz >> i) & 1) << (3 * i + 2));
        const int slotg = atomicAdd(&hist[code], 1);
        sb[slotg] = make_float4(x, y, z, __int_as_float(p));
        const int g = slotg >> 6;
        // owner wave = g&15, chunk index k = g>>4  (g = wv + 16k)
        sxy2[((g & 15) << 10) | ((g >> 4) << 6) | (slotg & 63)] = make_float2(x, y);
    }
    __syncthreads();   // drains scatter stores before readback

    // ---------- phase 0d: per-chunk z/d preload + AABB ----------
#define DECLP(k) float z##k, d##k;
    REPEAT16(DECLP)
#undef DECLP
    float abx0 = 0.f, aby0 = 0.f, abz0 = 0.f, abx1 = 0.f, aby1 = 0.f, abz1 = 0.f;

#define AABBPRE(k) { const int g = wv + ((k) << 4);                       \
    const float4 pt = sb[(g << 6) + lane];                                \
    z##k = pt.z;                                                          \
    d##k = 1e10f;                                                         \
    float mnx = pt.x, mxx = pt.x, mny = pt.y, mxy = pt.y,                 \
          mnz = pt.z, mxz = pt.z;                                         \
    _Pragma("unroll")                                                     \
    for (int m = 32; m >= 1; m >>= 1) {                                   \
        mnx = fminf(mnx, __shfl_xor(mnx, m, 64));                         \
        mxx = fmaxf(mxx, __shfl_xor(mxx, m, 64));                         \
        mny = fminf(mny, __shfl_xor(mny, m, 64));                         \
        mxy = fmaxf(mxy, __shfl_xor(mxy, m, 64));                         \
        mnz = fminf(mnz, __shfl_xor(mnz, m, 64));                         \
        mxz = fmaxf(mxz, __shfl_xor(mxz, m, 64));                         \
    }                                                                     \
    if (lane == (k)) { abx0 = mnx; abx1 = mxx; aby0 = mny; aby1 = mxy;    \
                       abz0 = mnz; abz1 = mxz; } }
    REPEAT16(AABBPRE)
#undef AABBPRE
    if (tid == 0) { slot[0] = 0ull; slot[1] = 0ull; slot[2] = 0ull; slot[3] = 0ull; }
    __syncthreads();

    // ---------- main loop ----------
    float bd = 0.0f;                  // my lane best distance
    unsigned btb = 0u;                // my lane best tie-break (valid w/ bd)
    int bestk = 0;
    int holder_ln = 0;                // wave-uniform
    float hx = 0.f, hy = 0.f, hz = 0.f;
    float cub = 1e10f;                // lane k: upper bound on chunk max d

    float ccx = bx[0], ccy = bx[1], ccz = bx[2];
    float prev_wd = 1e10f;

    for (int it = 0; it < NPOINT; ++it) {
        asm volatile("" : "+v"(z0), "+v"(z1), "+v"(z2),  "+v"(z3),
                          "+v"(z4), "+v"(z5), "+v"(z6),  "+v"(z7),
                          "+v"(z8), "+v"(z9), "+v"(z10), "+v"(z11),
                          "+v"(z12), "+v"(z13), "+v"(z14), "+v"(z15));

        if (tid == 0) {
            outc[it * 3 + 0] = ccx;
            outc[it * 3 + 1] = ccy;
            outc[it * 3 + 2] = ccz;
        }

        // --- AABB prune (lane k -> chunk wv+16k) ---
        bool active = false;
        if (lane < 16) {
            const float dxl = fmaxf(fmaxf(abx0 - ccx, ccx - abx1), 0.0f);
            const float dyl = fmaxf(fmaxf(aby0 - ccy, ccy - aby1), 0.0f);
            const float dzl = fmaxf(fmaxf(abz0 - ccz, ccz - abz1), 0.0f);
            const float mind2 = dxl * dxl + dyl * dyl + dzl * dzl;
            const float bound = fminf(prev_wd, cub);
            active = !(mind2 > bound * 1.001f);
        }
        const unsigned amask = (unsigned)(__ballot(active) & 0xFFFFull);

        // --- cub tighten: my chunk's update RAN iff my nibble is active ---
        if (lane < 16 && ((amask >> (lane & 12)) & 0xFu)) {
            const float dxm = fmaxf(ccx - abx0, abx1 - ccx);
            const float dym = fmaxf(ccy - aby0, aby1 - ccy);
            const float dzm = fmaxf(ccz - abz0, abz1 - ccz);
            const float maxd2 = dxm * dxm + dym * dym + dzm * dzm;
            cub = fminf(cub, maxd2);
        }

        // --- UPD: nibble-batched loads, unconditional min-update ---
        bool lredo = false;
        const int s2 = (wv << 10) | lane;   // float2 index, chunk stride 64
#define UPDM(k, p) {                                                      \
            const float dx = (p).x - ccx;                                 \
            const float dy = (p).y - ccy;                                 \
            const float dz = z##k - ccz;                                  \
            const float t  = (dx * dx + dy * dy) + dz * dz;               \
            const bool u   = t < d##k;                                    \
            d##k = u ? t : d##k;                                          \
            lredo |= (u && ((k) == bestk));                               \
        }
        if (amask & 0x000Fu) {
            const float2 p0 = sxy2[s2 +   0];
            const float2 p1 = sxy2[s2 +  64];
            const float2 p2 = sxy2[s2 + 128];
            const float2 p3 = sxy2[s2 + 192];
            UPDM(0, p0) UPDM(1, p1) UPDM(2, p2) UPDM(3, p3)
        }
        if (amask & 0x00F0u) {
            const float2 p0 = sxy2[s2 + 256];
            const float2 p1 = sxy2[s2 + 320];
            const float2 p2 = sxy2[s2 + 384];
            const float2 p3 = sxy2[s2 + 448];
            UPDM(4, p0) UPDM(5, p1) UPDM(6, p2) UPDM(7, p3)
        }
        if (amask & 0x0F00u) {
            const float2 p0 = sxy2[s2 + 512];
            const float2 p1 = sxy2[s2 + 576];
            const float2 p2 = sxy2[s2 + 640];
            const float2 p3 = sxy2[s2 + 704];
            UPDM(8, p0) UPDM(9, p1) UPDM(10, p2) UPDM(11, p3)
        }
        if (amask & 0xF000u) {
            const float2 p0 = sxy2[s2 + 768];
            const float2 p1 = sxy2[s2 + 832];
            const float2 p2 = sxy2[s2 + 896];
            const float2 p3 = sxy2[s2 + 960];
            UPDM(12, p0) UPDM(13, p1) UPDM(14, p2) UPDM(15, p3)
        }
#undef UPDM

        // --- per-lane best: recompute only when invalidated ---
        if (lredo) {
            float mx = d0;
#define LMX(k) mx = fmaxf(mx, d##k);
            REPEAT16(LMX)
#undef LMX
            unsigned tmask = 0u;
#define LMT(k) tmask |= (d##k == mx) ? (1u << (k)) : 0u;
            REPEAT16(LMT)
#undef LMT
            bd = mx;
            if (__popc(tmask) == 1) {
                bestk = __ffs(tmask) - 1;
                const int g = wv + (bestk << 4);
                const float* pw = (const float*)(sb + (g << 6) + lane);
                btb = 0x3FFFu - (unsigned)__float_as_int(pw[3]);
            } else {
                // exact rare path: smallest original index among tied chunks
                btb = 0u; bestk = 0;
#define TIE(k) if (tmask & (1u << (k))) {                                 \
                    const float* pw = (const float*)                      \
                        (sb + ((wv + ((k) << 4)) << 6) + lane);           \
                    const unsigned t = 0x3FFFu - (unsigned)__float_as_int(pw[3]); \
                    if (t > btb) { btb = t; bestk = (k); } }
                REPEAT16(TIE)
#undef TIE
            }
        }

        // --- wave best: reduce only when holder's best decreased ---
        const unsigned long long rb = __ballot(lredo);
        if ((rb >> holder_ln) & 1ull) {
            float m = bd;
            #pragma unroll
            for (int s = 32; s >= 1; s >>= 1) m = fmaxf(m, __shfl_xor(m, s, 64));
            const unsigned long long cmask = __ballot(bd == m);
            if (__popcll(cmask) == 1) {
                holder_ln = __ffsll((long long)cmask) - 1;
            } else {
                // exact u64 fallback on cross-lane d-ties (unique tb)
                const unsigned long long kv =
                    (((unsigned long long)__float_as_uint(bd)) << 32) |
                    ((unsigned long long)btb << 4);
                unsigned long long mm = kv;
                #pragma unroll
                for (int s = 32; s >= 1; s >>= 1) {
                    const unsigned long long o = __shfl_xor(mm, s, 64);
                    mm = o > mm ? o : mm;
                }
                holder_ln = __ffsll((long long)__ballot(kv == mm)) - 1;
            }
            if (lane == holder_ln) {
                const float2 hxy = sxy2[(wv << 10) | (bestk << 6) | lane];
                float zz = z0;
#define ZS(k) zz = (bestk == (k)) ? z##k : zz;
                REPEAT16(ZS)
#undef ZS
                hx = hxy.x; hy = hxy.y; hz = zz;
            }
        }

        // --- cross-wave: coords write + ONE atomicMax; ONE barrier ---
        if (lane == holder_ln) {
            wbc[(it & 1) * 16 + wv] = make_float4(hx, hy, hz, 0.0f);
            const unsigned long long key =
                (((unsigned long long)__float_as_uint(bd)) << 32) |
                ((unsigned long long)btb << 4) | (unsigned long long)wv;
            atomicMax(&slot[it & 3], key);
        }
        if (tid == 0) slot[(it + 1) & 3] = 0ull;
        __syncthreads();

        // --- winner: slot read and wbc[lane] read issue in parallel; ---
        // --- coords via v_readlane off readfirstlane'd winner id      ---
        const unsigned long long wk = slot[it & 3];
        float cwx = 0.f, cwy = 0.f, cwz = 0.f;
        if (lane < 16) {
            const float4 wf = wbc[(it & 1) * 16 + lane];
            cwx = wf.x; cwy = wf.y; cwz = wf.z;
        }
        prev_wd = __uint_as_float(
            (unsigned)__builtin_amdgcn_readfirstlane((int)(unsigned)(wk >> 32)));
        const int wwv = __builtin_amdgcn_readfirstlane((int)((unsigned)wk & 0xFu));
        ccx = __int_as_float(__builtin_amdgcn_readlane(__float_as_int(cwx), wwv));
        ccy = __int_as_float(__builtin_amdgcn_readlane(__float_as_int(cwy), wwv));
        ccz = __int_as_float(__builtin_amdgcn_readlane(__float_as_int(cwz), wwv));
    }

    // ---------- flush centroids ----------
    __syncthreads();
    float* outb = new_xyz + (size_t)b * NPOINT * 3;
    #pragma unroll
    for (int j = 0; j < 3; ++j) {
        const int idx = j * FPS_T + tid;
        outb[idx] = outc[idx];
    }
}

// ---------------------------------------------------------------------------
// K2: Ball query. One wave per query; ordered first-32 selection via ballot,
// early exit once 32 found. Exact arithmetic (contract off, rad2 = (float)0.04).
// ---------------------------------------------------------------------------
__global__ __launch_bounds__(256) void ballq_kernel(const float* __restrict__ xyz,
                                                    const float* __restrict__ new_xyz,
                                                    int* __restrict__ gidx) {
    #pragma clang fp contract(off)
    const int lane = threadIdx.x & 63;
    const int q    = blockIdx.x * 4 + (threadIdx.x >> 6);
    const int b    = q >> 10;                  // NPOINT = 1024
    const float* bx = xyz + (size_t)b * NN * 3;
    const float* nx = new_xyz + (size_t)q * 3;
    const float cx = nx[0], cy = nx[1], cz = nx[2];
    const float rad2 = 0.04f;  // f32 cast of python double 0.2**2 — NOT 0.2f*0.2f

    int* out  = gidx + (size_t)q * NSAMPLE;
    int taken = 0;
    int first = NN - 1;

    for (int chunk = 0; chunk < NN / 64 && taken < NSAMPLE; ++chunk) {
        const int   i  = chunk * 64 + lane;
        const float dx = cx - bx[i * 3 + 0];
        const float dy = cy - bx[i * 3 + 1];
        const float dz = cz - bx[i * 3 + 2];
        const float t  = dx * dx + dy * dy + dz * dz;
        const bool ok  = !(t > rad2);
        const unsigned long long m = __ballot(ok);
        const int cnt = __popcll(m);
        if (taken == 0 && cnt > 0) first = chunk * 64 + (__ffsll((long long)m) - 1);
        if (ok) {
            const int rank = taken + __popcll(m & ((1ull << lane) - 1ull));
            if (rank < NSAMPLE) out[rank] = i;
        }
        taken += cnt;
    }
    const int sat = taken < NSAMPLE ? taken : NSAMPLE;
    if (lane >= sat && lane < NSAMPLE) out[lane] = (taken > 0) ? first : (NN - 1);
}

// ---------------------------------------------------------------------------
// K3: gather feats -> LDS, MLP1 (67->64) + relu, MLP2 (64->128) + relu,
// max over the 32 samples. One 256-thread block per query. FMA allowed.
// ---------------------------------------------------------------------------
__global__ __launch_bounds__(256) void mlp_kernel(const float* __restrict__ xyz,
                                                  const float* __restrict__ points,
                                                  const float* __restrict__ w1,
                                                  const float* __restrict__ b1,
                                                  const float* __restrict__ w2,
                                                  const float* __restrict__ b2,
                                                  const float* __restrict__ new_xyz,
                                                  const int*   __restrict__ gidx,
                                                  float* __restrict__ new_points) {
    __shared__ __align__(16) float feats[32][68];
    __shared__ __align__(16) float h1s[32][64];
    __shared__ float pmax[2][128];

    const int q = blockIdx.x;
    const int b = q >> 10;
    const int t = threadIdx.x;

    {
        const int k  = t >> 3;
        const int l8 = t & 7;
        const int gi = gidx[q * 32 + k];
        const float* prow = points + ((size_t)b * NN + gi) * CC;
        const float4 v0 = *(const float4*)(prow + l8 * 8);
        const float4 v1 = *(const float4*)(prow + l8 * 8 + 4);
        *(float4*)&feats[k][4 + l8 * 8] = v0;
        *(float4*)&feats[k][8 + l8 * 8] = v1;
        if (l8 == 0) {
            const float* pr = xyz + ((size_t)b * NN + gi) * 3;
            const float* nr = new_xyz + (size_t)q * 3;
            feats[k][0] = pr[0] - nr[0];
            feats[k][1] = pr[1] - nr[1];
            feats[k][2] = pr[2] - nr[2];
        }
    }

    const int c1 = t & 63;
    float w1r[67];
    #pragma unroll
    for (int j = 0; j < 67; ++j) w1r[j] = w1[c1 * 67 + j];
    const float bb1 = b1[c1];
    __syncthreads();

    const int kg = t >> 6;
    #pragma unroll
    for (int kk = 0; kk < 8; ++kk) {
        const int kr = kg * 8 + kk;
        float acc = bb1;
        acc += feats[kr][0] * w1r[0] + feats[kr][1] * w1r[1] + feats[kr][2] * w1r[2];
        #pragma unroll
        for (int j = 0; j < 64; j += 4) {
            const float4 f = *(const float4*)&feats[kr][4 + j];
            acc += f.x * w1r[3 + j] + f.y * w1r[4 + j] + f.z * w1r[5 + j] + f.w * w1r[6 + j];
        }
        h1s[kr][c1] = fmaxf(acc, 0.0f);
    }

    const int o2 = t & 127;
    const int kh = t >> 7;
    float w2r[64];
    #pragma unroll
    for (int j = 0; j < 64; ++j) w2r[j] = w2[o2 * 64 + j];
    const float bb2 = b2[o2];
    __syncthreads();

    float mx = -INFINITY;
    #pragma unroll
    for (int kk = 0; kk < 16; ++kk) {
        const int kr = kh * 16 + kk;
        float acc = bb2;
        #pragma unroll
        for (int j = 0; j < 64; j += 4) {
            const float4 h = *(const float4*)&h1s[kr][j];
            acc += h.x * w2r[j] + h.y * w2r[j + 1] + h.z * w2r[j + 2] + h.w * w2r[j + 3];
        }
        mx = fmaxf(mx, fmaxf(acc, 0.0f));
    }
    pmax[kh][o2] = mx;
    __syncthreads();
    if (t < 128) {
        new_points[(size_t)q * 128 + t] = fmaxf(pmax[0][t], pmax[1][t]);
    }
}

// ---------------------------------------------------------------------------
extern "C" void kernel_launch(void* const* d_in, const int* in_sizes, int n_in,
                              void* d_out, int out_size, void* d_ws, size_t ws_size,
                              hipStream_t stream) {
    const float* xyz    = (const float*)d_in[0];
    const float* points = (const float*)d_in[1];
    const float* w1     = (const float*)d_in[2];
    const float* b1     = (const float*)d_in[3];
    const float* w2     = (const float*)d_in[4];
    const float* b2     = (const float*)d_in[5];

    float* out_newxyz    = (float*)d_out;
    float* out_newpoints = (float*)d_out + (size_t)BB * NPOINT * 3;
    int*    gidx    = (int*)d_ws;                                   // 512 KB
    float4* sortbuf = (float4*)((char*)d_ws + (size_t)512 * 1024);  // 1 MB

    // LDS map: sxy2 @0 (131072) | hist/outc alias @131072 (16384/12288) |
    // wbc @147456 (512) | slot @147968 (32) | wsum @148000 (64) -> 148064
    const int fps_lds = 148064;
    (void)hipFuncSetAttribute((const void*)fps_kernel,
                              hipFuncAttributeMaxDynamicSharedMemorySize,
                              fps_lds);

    fps_kernel<<<BB, FPS_T, fps_lds, stream>>>(xyz, out_newxyz, sortbuf);
    ballq_kernel<<<(BB * NPOINT) / 4, 256, 0, stream>>>(xyz, out_newxyz, gidx);
    mlp_kernel<<<BB * NPOINT, 256, 0, stream>>>(xyz, points, w1, b1, w2, b2,
                                                out_newxyz, gidx, out_newpoints);
}

// Round 5
// 1692.777 us; speedup vs baseline: 1.3103x; 1.0227x over previous
//
#include <hip/hip_runtime.h>

#define BB 4
#define NN 16384
#define CC 64
#define NPOINT 1024
#define NSAMPLE 32

#define FPS_T 1024
#define NCHUNK 256          // 64 points per chunk
#define NCELL 4096          // 16^3 Morton cells

#define REPEAT16(M) M(0) M(1) M(2) M(3) M(4) M(5) M(6) M(7) \
                    M(8) M(9) M(10) M(11) M(12) M(13) M(14) M(15)

// ---------------------------------------------------------------------------
// K1: Pruned FPS, 16 waves, event-driven reductions, atomic cross-wave
// reduce, no global ops in the iteration loop.
//  == R0 (1420us steady, VGPR=56, ZERO scratch) + ONE isolated change ==
//  R1-R4 lesson: any variant pushing peak pressure past the 64-VGPR cap
//  (register-resident xy, nibble/pair load batching) pays steady scratch
//  latency + a ~42ms scratch-arena cold dispatch (~+170us in the metric).
//  The only pressure-NEUTRAL R1 idea, never tested alone, is the serial
//  tail fix, applied here:
//   - OLD tail: barrier -> slot read (~120cy) -> DEPENDENT wbc[wwv] read
//     (~120cy) -> next prune.  Two serial LDS latencies.
//   - NEW tail: slot read and wbc[lane] (lanes<16) issue IN PARALLEL under
//     one waitcnt; winner id via readfirstlane; coords via v_readlane
//     (SALU/VALU, results in SGPRs -> zero added VGPR pressure).
//  Everything else is byte-identical to R0:
//  - Morton counting-sort: sb (global, float4 x,y,z,orig) + sxy (LDS float2).
//  - Wave wv owns chunks {wv+16k}; lane L holds u64 key##k =
//    d_bits<<32 | tb<<4 (tb = 0x3FFF-orig, globally unique) — LOOP-CARRIED.
//    z##k asm-pinned. AABB of chunk wv+16k in lane-k registers.
//  - Prune: chunk active iff mind2(AABB,c) <= min(prev_wd, cub)*1.001 where
//    cub = min over processed centroids of maxdist2(AABB,c) >= chunk max d
//    (maintained in the test itself, lane k). Exact-conservative skip.
//  - Event-driven: lane best recomputed only when its best's key decreased;
//    wave butterfly only when holder lane's best decreased. Unique keys ->
//    no tie paths; first-original-index tie-break exact.
//  - Cross-wave: holder writes coords to wbc dbuf + ONE atomicMax of
//    (bkey|wv) into slot[it&3]; ONE barrier.
//  - Centroids buffered in LDS outc[], flushed after the loop.
// Bit-exact: contract(off), (dx*dx+dy*dy)+dz*dz order, min-as-cond-update.
// ---------------------------------------------------------------------------
__global__ __launch_bounds__(FPS_T) void fps_kernel(const float* __restrict__ xyz,
                                                    float* __restrict__ new_xyz,
                                                    float4* __restrict__ sorted) {
    #pragma clang fp contract(off)
    extern __shared__ char smem_raw[];
    float2* sxy  = (float2*)smem_raw;                         // 131072 B
    int*    hist = (int*)(smem_raw + 131072);                 // 16384 B (setup)
    float*  outc = (float*)(smem_raw + 131072);               // 12288 B (alias)
    float4* wbc  = (float4*)(smem_raw + 153984);              // [2][16] 512 B
    unsigned long long* slot = (unsigned long long*)(smem_raw + 154496); // [4]
    int*    wsum = (int*)(smem_raw + 154528);                 // [16]

    const int b    = blockIdx.x;
    const int tid  = threadIdx.x;
    const int lane = tid & 63;
    const int wv   = tid >> 6;                  // 0..15
    const float* bx = xyz + (size_t)b * NN * 3;
    float4* sb = sorted + (size_t)b * NN;

    // ---------- phase 0a: histogram of Morton cell codes ----------
    #pragma unroll
    for (int j = 0; j < 4; ++j) hist[j * FPS_T + tid] = 0;
    __syncthreads();

    #pragma unroll
    for (int j = 0; j < 16; ++j) {
        const int p = j * FPS_T + tid;
        const float x = bx[p * 3 + 0], y = bx[p * 3 + 1], z = bx[p * 3 + 2];
        int cx = (int)(x * 16.0f); cx = cx > 15 ? 15 : (cx < 0 ? 0 : cx);
        int cy = (int)(y * 16.0f); cy = cy > 15 ? 15 : (cy < 0 ? 0 : cy);
        int cz = (int)(z * 16.0f); cz = cz > 15 ? 15 : (cz < 0 ? 0 : cz);
        int code = 0;
        #pragma unroll
        for (int i = 0; i < 4; ++i)
            code |= (((cx >> i) & 1) << (3 * i)) |
                    (((cy >> i) & 1) << (3 * i + 1)) |
                    (((cz >> i) & 1) << (3 * i + 2));
        atomicAdd(&hist[code], 1);
    }
    __syncthreads();

    // ---------- phase 0b: exclusive scan ----------
    {
        const int h0 = hist[4 * tid + 0], h1 = hist[4 * tid + 1];
        const int h2 = hist[4 * tid + 2], h3 = hist[4 * tid + 3];
        const int s  = h0 + h1 + h2 + h3;
        int v = s;
        #pragma unroll
        for (int o = 1; o < 64; o <<= 1) {
            const int u = __shfl_up(v, o, 64);
            if (lane >= o) v += u;
        }
        if (lane == 63) wsum[wv] = v;
        __syncthreads();
        int base = 0;
        for (int w = 0; w < wv; ++w) base += wsum[w];
        const int e0 = base + v - s;
        hist[4 * tid + 0] = e0;
        hist[4 * tid + 1] = e0 + h0;
        hist[4 * tid + 2] = e0 + h0 + h1;
        hist[4 * tid + 3] = e0 + h0 + h1 + h2;
    }
    __syncthreads();

    // ---------- phase 0c: scatter to global sb AND LDS sxy ----------
    #pragma unroll
    for (int j = 0; j < 16; ++j) {
        const int p = j * FPS_T + tid;
        const float x = bx[p * 3 + 0], y = bx[p * 3 + 1], z = bx[p * 3 + 2];
        int cx = (int)(x * 16.0f); cx = cx > 15 ? 15 : (cx < 0 ? 0 : cx);
        int cy = (int)(y * 16.0f); cy = cy > 15 ? 15 : (cy < 0 ? 0 : cy);
        int cz = (int)(z * 16.0f); cz = cz > 15 ? 15 : (cz < 0 ? 0 : cz);
        int code = 0;
        #pragma unroll
        for (int i = 0; i < 4; ++i)
            code |= (((cx >> i) & 1) << (3 * i)) |
                    (((cy >> i) & 1) << (3 * i + 1)) |
                    (((cz >> i) & 1) << (3 * i + 2));
        const int slotg = atomicAdd(&hist[code], 1);
        sb[slotg]  = make_float4(x, y, z, __int_as_float(p));
        sxy[slotg] = make_float2(x, y);
    }
    __syncthreads();   // drains scatter stores before readback

    // ---------- phase 0d: per-chunk AABB + z/key preload ----------
#define DECLZ(k) float z##k; unsigned long long key##k;
    REPEAT16(DECLZ)
#undef DECLZ
    float abx0 = 0.f, aby0 = 0.f, abz0 = 0.f, abx1 = 0.f, aby1 = 0.f, abz1 = 0.f;

#define AABBPRE(k) { const int g = wv + ((k) << 4);                       \
    const float4 pt = sb[(g << 6) + lane];                                \
    z##k = pt.z;                                                          \
    key##k = (((unsigned long long)__float_as_uint(1e10f)) << 32) |       \
             ((unsigned long long)(0x3FFFu -                              \
                    (unsigned)__float_as_int(pt.w)) << 4);                \
    float mnx = pt.x, mxx = pt.x, mny = pt.y, mxy = pt.y,                 \
          mnz = pt.z, mxz = pt.z;                                         \
    _Pragma("unroll")                                                     \
    for (int m = 32; m >= 1; m >>= 1) {                                   \
        mnx = fminf(mnx, __shfl_xor(mnx, m, 64));                         \
        mxx = fmaxf(mxx, __shfl_xor(mxx, m, 64));                         \
        mny = fminf(mny, __shfl_xor(mny, m, 64));                         \
        mxy = fmaxf(mxy, __shfl_xor(mxy, m, 64));                         \
        mnz = fminf(mnz, __shfl_xor(mnz, m, 64));                         \
        mxz = fmaxf(mxz, __shfl_xor(mxz, m, 64));                         \
    }                                                                     \
    if (lane == (k)) { abx0 = mnx; abx1 = mxx; aby0 = mny; aby1 = mxy;    \
                       abz0 = mnz; abz1 = mxz; } }
    REPEAT16(AABBPRE)
#undef AABBPRE
    if (tid == 0) { slot[0] = 0ull; slot[1] = 0ull; slot[2] = 0ull; slot[3] = 0ull; }
    __syncthreads();

    // ---------- main loop ----------
    unsigned long long bkey = 0ull;   // my lane best (max over key0..15)
    int bestk = 0;
    int holder_ln = 0;                // wave-uniform
    float hx = 0.f, hy = 0.f, hz = 0.f;
    float cub = 1e10f;                // lane k: upper bound on chunk max d

    float ccx = bx[0], ccy = bx[1], ccz = bx[2];
    float prev_wd = 1e10f;

    for (int it = 0; it < NPOINT; ++it) {
        asm volatile("" : "+v"(z0), "+v"(z1), "+v"(z2),  "+v"(z3),
                          "+v"(z4), "+v"(z5), "+v"(z6),  "+v"(z7),
                          "+v"(z8), "+v"(z9), "+v"(z10), "+v"(z11),
                          "+v"(z12), "+v"(z13), "+v"(z14), "+v"(z15));

        if (tid == 0) {
            outc[it * 3 + 0] = ccx;
            outc[it * 3 + 1] = ccy;
            outc[it * 3 + 2] = ccz;
        }

        // --- AABB prune + cub maintenance (lane k -> chunk wv+16k) ---
        bool active = false;
        if (lane < 16) {
            const float dxl = fmaxf(fmaxf(abx0 - ccx, ccx - abx1), 0.0f);
            const float dyl = fmaxf(fmaxf(aby0 - ccy, ccy - aby1), 0.0f);
            const float dzl = fmaxf(fmaxf(abz0 - ccz, ccz - abz1), 0.0f);
            const float mind2 = dxl * dxl + dyl * dyl + dzl * dzl;
            const float bound = fminf(prev_wd, cub);
            active = !(mind2 > bound * 1.001f);
            if (active) {
                // chunk will be processed with this centroid: tighten cub
                const float dxm = fmaxf(ccx - abx0, abx1 - ccx);
                const float dym = fmaxf(ccy - aby0, aby1 - ccy);
                const float dzm = fmaxf(ccz - abz0, abz1 - ccz);
                const float maxd2 = dxm * dxm + dym * dym + dzm * dzm;
                cub = fminf(cub, maxd2);
            }
        }
        const unsigned amask = (unsigned)(__ballot(active) & 0xFFFFull);

        bool lredo = false;
#define UPD(k) if (amask & (1u << (k))) {                                 \
            const int g = wv + ((k) << 4);                                \
            const float2 xy = sxy[(g << 6) + lane];                       \
            const float dx = xy.x - ccx;                                  \
            const float dy = xy.y - ccy;                                  \
            const float dz = z##k - ccz;                                  \
            const float t  = (dx * dx + dy * dy) + dz * dz;               \
            const float dold = __uint_as_float((unsigned)(key##k >> 32)); \
            if (t < dold) {                                               \
                key##k = (((unsigned long long)__float_as_uint(t)) << 32) \
                         | (key##k & 0xFFFFFFFFull);                      \
                lredo |= ((k) == bestk);                                  \
            }                                                             \
        }
        if (amask & 0x000Fu) { UPD(0)  UPD(1)  UPD(2)  UPD(3)  }
        if (amask & 0x00F0u) { UPD(4)  UPD(5)  UPD(6)  UPD(7)  }
        if (amask & 0x0F00u) { UPD(8)  UPD(9)  UPD(10) UPD(11) }
        if (amask & 0xF000u) { UPD(12) UPD(13) UPD(14) UPD(15) }
#undef UPD

        // --- per-lane best: recompute only when invalidated ---
        if (lredo) {
            bkey = 0ull; bestk = 0;
#define LM(k) if (key##k > bkey) { bkey = key##k; bestk = (k); }
            REPEAT16(LM)
#undef LM
        }

        // --- wave best: butterfly only when holder's best decreased ---
        const unsigned long long rb = __ballot(lredo);
        if ((rb >> holder_ln) & 1ull) {
            unsigned long long m = bkey;
            #pragma unroll
            for (int s = 32; s >= 1; s >>= 1) {
                const unsigned long long o = __shfl_xor(m, s, 64);
                m = o > m ? o : m;
            }
            holder_ln = __ffsll((long long)__ballot(bkey == m)) - 1;  // unique
            if (lane == holder_ln) {
                const float2 xy = sxy[((wv + (bestk << 4)) << 6) + lane];
                float zz = z0;
#define ZS(k) zz = (bestk == (k)) ? z##k : zz;
                REPEAT16(ZS)
#undef ZS
                hx = xy.x; hy = xy.y; hz = zz;
            }
        }

        // --- cross-wave: coords write + ONE atomicMax; ONE barrier ---
        if (lane == holder_ln) {
            wbc[(it & 1) * 16 + wv] = make_float4(hx, hy, hz, 0.0f);
            atomicMax(&slot[it & 3], bkey | (unsigned long long)wv);
        }
        if (tid == 0) slot[(it + 1) & 3] = 0ull;
        __syncthreads();

        // --- winner: slot read and wbc[lane] read issue in PARALLEL ---
        // --- (one waitcnt); coords via v_readlane off readfirstlane'd ---
        // --- winner id — removes the old dependent 2nd LDS latency.   ---
        const unsigned long long wk = slot[it & 3];
        float cwx = 0.f, cwy = 0.f, cwz = 0.f;
        if (lane < 16) {
            const float4 wf = wbc[(it & 1) * 16 + lane];
            cwx = wf.x; cwy = wf.y; cwz = wf.z;
        }
        prev_wd = __uint_as_float(
            (unsigned)__builtin_amdgcn_readfirstlane((int)(unsigned)(wk >> 32)));
        const int wwv = __builtin_amdgcn_readfirstlane((int)((unsigned)wk & 0xFu));
        ccx = __int_as_float(__builtin_amdgcn_readlane(__float_as_int(cwx), wwv));
        ccy = __int_as_float(__builtin_amdgcn_readlane(__float_as_int(cwy), wwv));
        ccz = __int_as_float(__builtin_amdgcn_readlane(__float_as_int(cwz), wwv));
    }

    // ---------- flush centroids ----------
    __syncthreads();
    float* outb = new_xyz + (size_t)b * NPOINT * 3;
    #pragma unroll
    for (int j = 0; j < 3; ++j) {
        const int idx = j * FPS_T + tid;
        outb[idx] = outc[idx];
    }
}

// ---------------------------------------------------------------------------
// K2: Ball query. One wave per query; ordered first-32 selection via ballot,
// early exit once 32 found. Exact arithmetic (contract off, rad2 = (float)0.04).
// ---------------------------------------------------------------------------
__global__ __launch_bounds__(256) void ballq_kernel(const float* __restrict__ xyz,
                                                    const float* __restrict__ new_xyz,
                                                    int* __restrict__ gidx) {
    #pragma clang fp contract(off)
    const int lane = threadIdx.x & 63;
    const int q    = blockIdx.x * 4 + (threadIdx.x >> 6);
    const int b    = q >> 10;                  // NPOINT = 1024
    const float* bx = xyz + (size_t)b * NN * 3;
    const float* nx = new_xyz + (size_t)q * 3;
    const float cx = nx[0], cy = nx[1], cz = nx[2];
    const float rad2 = 0.04f;  // f32 cast of python double 0.2**2 — NOT 0.2f*0.2f

    int* out  = gidx + (size_t)q * NSAMPLE;
    int taken = 0;
    int first = NN - 1;

    for (int chunk = 0; chunk < NN / 64 && taken < NSAMPLE; ++chunk) {
        const int   i  = chunk * 64 + lane;
        const float dx = cx - bx[i * 3 + 0];
        const float dy = cy - bx[i * 3 + 1];
        const float dz = cz - bx[i * 3 + 2];
        const float t  = dx * dx + dy * dy + dz * dz;
        const bool ok  = !(t > rad2);
        const unsigned long long m = __ballot(ok);
        const int cnt = __popcll(m);
        if (taken == 0 && cnt > 0) first = chunk * 64 + (__ffsll((long long)m) - 1);
        if (ok) {
            const int rank = taken + __popcll(m & ((1ull << lane) - 1ull));
            if (rank < NSAMPLE) out[rank] = i;
        }
        taken += cnt;
    }
    const int sat = taken < NSAMPLE ? taken : NSAMPLE;
    if (lane >= sat && lane < NSAMPLE) out[lane] = (taken > 0) ? first : (NN - 1);
}

// ---------------------------------------------------------------------------
// K3: gather feats -> LDS, MLP1 (67->64) + relu, MLP2 (64->128) + relu,
// max over the 32 samples. One 256-thread block per query. FMA allowed.
// ---------------------------------------------------------------------------
__global__ __launch_bounds__(256) void mlp_kernel(const float* __restrict__ xyz,
                                                  const float* __restrict__ points,
                                                  const float* __restrict__ w1,
                                                  const float* __restrict__ b1,
                                                  const float* __restrict__ w2,
                                                  const float* __restrict__ b2,
                                                  const float* __restrict__ new_xyz,
                                                  const int*   __restrict__ gidx,
                                                  float* __restrict__ new_points) {
    __shared__ __align__(16) float feats[32][68];
    __shared__ __align__(16) float h1s[32][64];
    __shared__ float pmax[2][128];

    const int q = blockIdx.x;
    const int b = q >> 10;
    const int t = threadIdx.x;

    {
        const int k  = t >> 3;
        const int l8 = t & 7;
        const int gi = gidx[q * 32 + k];
        const float* prow = points + ((size_t)b * NN + gi) * CC;
        const float4 v0 = *(const float4*)(prow + l8 * 8);
        const float4 v1 = *(const float4*)(prow + l8 * 8 + 4);
        *(float4*)&feats[k][4 + l8 * 8] = v0;
        *(float4*)&feats[k][8 + l8 * 8] = v1;
        if (l8 == 0) {
            const float* pr = xyz + ((size_t)b * NN + gi) * 3;
            const float* nr = new_xyz + (size_t)q * 3;
            feats[k][0] = pr[0] - nr[0];
            feats[k][1] = pr[1] - nr[1];
            feats[k][2] = pr[2] - nr[2];
        }
    }

    const int c1 = t & 63;
    float w1r[67];
    #pragma unroll
    for (int j = 0; j < 67; ++j) w1r[j] = w1[c1 * 67 + j];
    const float bb1 = b1[c1];
    __syncthreads();

    const int kg = t >> 6;
    #pragma unroll
    for (int kk = 0; kk < 8; ++kk) {
        const int kr = kg * 8 + kk;
        float acc = bb1;
        acc += feats[kr][0] * w1r[0] + feats[kr][1] * w1r[1] + feats[kr][2] * w1r[2];
        #pragma unroll
        for (int j = 0; j < 64; j += 4) {
            const float4 f = *(const float4*)&feats[kr][4 + j];
            acc += f.x * w1r[3 + j] + f.y * w1r[4 + j] + f.z * w1r[5 + j] + f.w * w1r[6 + j];
        }
        h1s[kr][c1] = fmaxf(acc, 0.0f);
    }

    const int o2 = t & 127;
    const int kh = t >> 7;
    float w2r[64];
    #pragma unroll
    for (int j = 0; j < 64; ++j) w2r[j] = w2[o2 * 64 + j];
    const float bb2 = b2[o2];
    __syncthreads();

    float mx = -INFINITY;
    #pragma unroll
    for (int kk = 0; kk < 16; ++kk) {
        const int kr = kh * 16 + kk;
        float acc = bb2;
        #pragma unroll
        for (int j = 0; j < 64; j += 4) {
            const float4 h = *(const float4*)&h1s[kr][j];
            acc += h.x * w2r[j] + h.y * w2r[j + 1] + h.z * w2r[j + 2] + h.w * w2r[j + 3];
        }
        mx = fmaxf(mx, fmaxf(acc, 0.0f));
    }
    pmax[kh][o2] = mx;
    __syncthreads();
    if (t < 128) {
        new_points[(size_t)q * 128 + t] = fmaxf(pmax[0][t], pmax[1][t]);
    }
}

// ---------------------------------------------------------------------------
extern "C" void kernel_launch(void* const* d_in, const int* in_sizes, int n_in,
                              void* d_out, int out_size, void* d_ws, size_t ws_size,
                              hipStream_t stream) {
    const float* xyz    = (const float*)d_in[0];
    const float* points = (const float*)d_in[1];
    const float* w1     = (const float*)d_in[2];
    const float* b1     = (const float*)d_in[3];
    const float* w2     = (const float*)d_in[4];
    const float* b2     = (const float*)d_in[5];

    float* out_newxyz    = (float*)d_out;
    float* out_newpoints = (float*)d_out + (size_t)BB * NPOINT * 3;
    int*    gidx    = (int*)d_ws;                                   // 512 KB
    float4* sortbuf = (float4*)((char*)d_ws + (size_t)512 * 1024);  // 1 MB

    // LDS map: sxy 131072 | hist/outc alias @131072 (16384) | wbc @153984
    // (512) | slot @154496 (32) | wsum @154528 (64)
    const int fps_lds = 154816;
    (void)hipFuncSetAttribute((const void*)fps_kernel,
                              hipFuncAttributeMaxDynamicSharedMemorySize,
                              fps_lds);

    fps_kernel<<<BB, FPS_T, fps_lds, stream>>>(xyz, out_newxyz, sortbuf);
    ballq_kernel<<<(BB * NPOINT) / 4, 256, 0, stream>>>(xyz, out_newxyz, gidx);
    mlp_kernel<<<BB * NPOINT, 256, 0, stream>>>(xyz, points, w1, b1, w2, b2,
                                                out_newxyz, gidx, out_newpoints);
}

// Round 6
// 1667.693 us; speedup vs baseline: 1.3300x; 1.0150x over previous
//
#include <hip/hip_runtime.h>

#define BB 4
#define NN 16384
#define CC 64
#define NPOINT 1024
#define NSAMPLE 32

#define FPS_T 1024
#define NCHUNK 256          // 64 points per chunk
#define NCELL 4096          // 16^3 Morton cells

#define REPEAT16(M) M(0) M(1) M(2) M(3) M(4) M(5) M(6) M(7) \
                    M(8) M(9) M(10) M(11) M(12) M(13) M(14) M(15)

// ---------------------------------------------------------------------------
// K1: Pruned FPS, 16 waves, event-driven reductions, atomic cross-wave
// reduce, no global ops in the iteration loop.
//  == R0 (1420us steady, VGPR=56, zero scratch) + TWO pressure-neutral edits ==
//  R5 lesson: readlane/SGPR tail = -98us; REVERTED to R0's broadcast tail.
//  Edits this round (both pressure <= +4 regs):
//   1. sxy2 permuted LDS layout [wv][k][lane]: a wave's chunk pair (k,k+1)
//      sits 512B apart -> both ds_read_b64 issue back-to-back (mergeable to
//      ds_read2st64_b64): ONE LDS latency per PAIR, not per chunk.
//   2. UPD guarded per pair (amask & 3<<k); both chunks of an active pair
//      updated unconditionally (min-update is exact regardless of pruning;
//      R4-proven). cub tighten gated on pair-active (update really ran).
//      Morton-consecutive chunks are spatially adjacent -> actives cluster
//      in pairs, so pair guards skip nearly as well as singles.
//  Everything else byte-identical to R0:
//  - Morton counting-sort: sb (global, float4 x,y,z,orig) + sxy2 (LDS).
//  - Wave wv owns chunks {wv+16k}; lane L holds u64 key##k =
//    d_bits<<32 | tb<<4 (tb = 0x3FFF-orig, globally unique) — LOOP-CARRIED.
//    z##k asm-pinned. AABB of chunk wv+16k in lane-k registers.
//  - Prune: chunk active iff mind2(AABB,c) <= min(prev_wd, cub)*1.001,
//    cub = min over processed centroids of maxdist2(AABB,c) >= chunk max d.
//  - Event-driven: lane best recomputed only when its best's key decreased;
//    wave butterfly only when holder lane's best decreased. Unique keys ->
//    no tie paths; first-original-index tie-break exact.
//  - Cross-wave: holder writes coords to wbc dbuf + ONE atomicMax of
//    (bkey|wv) into slot[it&3]; ONE barrier; broadcast slot read -> wv ->
//    broadcast coords read (R0 tail).
//  - Centroids buffered in LDS outc[], flushed after the loop.
// Bit-exact: contract(off), (dx*dx+dy*dy)+dz*dz order, min-as-cond-update.
// ---------------------------------------------------------------------------
__global__ __launch_bounds__(FPS_T) void fps_kernel(const float* __restrict__ xyz,
                                                    float* __restrict__ new_xyz,
                                                    float4* __restrict__ sorted) {
    #pragma clang fp contract(off)
    extern __shared__ char smem_raw[];
    float2* sxy2 = (float2*)smem_raw;                         // 131072 B [wv][k][lane]
    int*    hist = (int*)(smem_raw + 131072);                 // 16384 B (setup)
    float*  outc = (float*)(smem_raw + 131072);               // 12288 B (alias)
    float4* wbc  = (float4*)(smem_raw + 147456);              // [2][16] 512 B
    unsigned long long* slot = (unsigned long long*)(smem_raw + 147968); // [4]
    int*    wsum = (int*)(smem_raw + 148000);                 // [16]

    const int b    = blockIdx.x;
    const int tid  = threadIdx.x;
    const int lane = tid & 63;
    const int wv   = tid >> 6;                  // 0..15
    const float* bx = xyz + (size_t)b * NN * 3;
    float4* sb = sorted + (size_t)b * NN;

    // ---------- phase 0a: histogram of Morton cell codes ----------
    #pragma unroll
    for (int j = 0; j < 4; ++j) hist[j * FPS_T + tid] = 0;
    __syncthreads();

    #pragma unroll
    for (int j = 0; j < 16; ++j) {
        const int p = j * FPS_T + tid;
        const float x = bx[p * 3 + 0], y = bx[p * 3 + 1], z = bx[p * 3 + 2];
        int cx = (int)(x * 16.0f); cx = cx > 15 ? 15 : (cx < 0 ? 0 : cx);
        int cy = (int)(y * 16.0f); cy = cy > 15 ? 15 : (cy < 0 ? 0 : cy);
        int cz = (int)(z * 16.0f); cz = cz > 15 ? 15 : (cz < 0 ? 0 : cz);
        int code = 0;
        #pragma unroll
        for (int i = 0; i < 4; ++i)
            code |= (((cx >> i) & 1) << (3 * i)) |
                    (((cy >> i) & 1) << (3 * i + 1)) |
                    (((cz >> i) & 1) << (3 * i + 2));
        atomicAdd(&hist[code], 1);
    }
    __syncthreads();

    // ---------- phase 0b: exclusive scan ----------
    {
        const int h0 = hist[4 * tid + 0], h1 = hist[4 * tid + 1];
        const int h2 = hist[4 * tid + 2], h3 = hist[4 * tid + 3];
        const int s  = h0 + h1 + h2 + h3;
        int v = s;
        #pragma unroll
        for (int o = 1; o < 64; o <<= 1) {
            const int u = __shfl_up(v, o, 64);
            if (lane >= o) v += u;
        }
        if (lane == 63) wsum[wv] = v;
        __syncthreads();
        int base = 0;
        for (int w = 0; w < wv; ++w) base += wsum[w];
        const int e0 = base + v - s;
        hist[4 * tid + 0] = e0;
        hist[4 * tid + 1] = e0 + h0;
        hist[4 * tid + 2] = e0 + h0 + h1;
        hist[4 * tid + 3] = e0 + h0 + h1 + h2;
    }
    __syncthreads();

    // ---------- phase 0c: scatter to global sb AND LDS sxy2 (permuted) ----------
    #pragma unroll
    for (int j = 0; j < 16; ++j) {
        const int p = j * FPS_T + tid;
        const float x = bx[p * 3 + 0], y = bx[p * 3 + 1], z = bx[p * 3 + 2];
        int cx = (int)(x * 16.0f); cx = cx > 15 ? 15 : (cx < 0 ? 0 : cx);
        int cy = (int)(y * 16.0f); cy = cy > 15 ? 15 : (cy < 0 ? 0 : cy);
        int cz = (int)(z * 16.0f); cz = cz > 15 ? 15 : (cz < 0 ? 0 : cz);
        int code = 0;
        #pragma unroll
        for (int i = 0; i < 4; ++i)
            code |= (((cx >> i) & 1) << (3 * i)) |
                    (((cy >> i) & 1) << (3 * i + 1)) |
                    (((cz >> i) & 1) << (3 * i + 2));
        const int slotg = atomicAdd(&hist[code], 1);
        sb[slotg] = make_float4(x, y, z, __int_as_float(p));
        const int g = slotg >> 6;
        // owner wave = g&15, chunk index k = g>>4  (g = wv + 16k)
        sxy2[((g & 15) << 10) | ((g >> 4) << 6) | (slotg & 63)] = make_float2(x, y);
    }
    __syncthreads();   // drains scatter stores before readback

    // ---------- phase 0d: per-chunk AABB + z/key preload ----------
#define DECLZ(k) float z##k; unsigned long long key##k;
    REPEAT16(DECLZ)
#undef DECLZ
    float abx0 = 0.f, aby0 = 0.f, abz0 = 0.f, abx1 = 0.f, aby1 = 0.f, abz1 = 0.f;

#define AABBPRE(k) { const int g = wv + ((k) << 4);                       \
    const float4 pt = sb[(g << 6) + lane];                                \
    z##k = pt.z;                                                          \
    key##k = (((unsigned long long)__float_as_uint(1e10f)) << 32) |       \
             ((unsigned long long)(0x3FFFu -                              \
                    (unsigned)__float_as_int(pt.w)) << 4);                \
    float mnx = pt.x, mxx = pt.x, mny = pt.y, mxy = pt.y,                 \
          mnz = pt.z, mxz = pt.z;                                         \
    _Pragma("unroll")                                                     \
    for (int m = 32; m >= 1; m >>= 1) {                                   \
        mnx = fminf(mnx, __shfl_xor(mnx, m, 64));                         \
        mxx = fmaxf(mxx, __shfl_xor(mxx, m, 64));                         \
        mny = fminf(mny, __shfl_xor(mny, m, 64));                         \
        mxy = fmaxf(mxy, __shfl_xor(mxy, m, 64));                         \
        mnz = fminf(mnz, __shfl_xor(mnz, m, 64));                         \
        mxz = fmaxf(mxz, __shfl_xor(mxz, m, 64));                         \
    }                                                                     \
    if (lane == (k)) { abx0 = mnx; abx1 = mxx; aby0 = mny; aby1 = mxy;    \
                       abz0 = mnz; abz1 = mxz; } }
    REPEAT16(AABBPRE)
#undef AABBPRE
    if (tid == 0) { slot[0] = 0ull; slot[1] = 0ull; slot[2] = 0ull; slot[3] = 0ull; }
    __syncthreads();

    // ---------- main loop ----------
    unsigned long long bkey = 0ull;   // my lane best (max over key0..15)
    int bestk = 0;
    int holder_ln = 0;                // wave-uniform
    float hx = 0.f, hy = 0.f, hz = 0.f;
    float cub = 1e10f;                // lane k: upper bound on chunk max d

    float ccx = bx[0], ccy = bx[1], ccz = bx[2];
    float prev_wd = 1e10f;

    for (int it = 0; it < NPOINT; ++it) {
        asm volatile("" : "+v"(z0), "+v"(z1), "+v"(z2),  "+v"(z3),
                          "+v"(z4), "+v"(z5), "+v"(z6),  "+v"(z7),
                          "+v"(z8), "+v"(z9), "+v"(z10), "+v"(z11),
                          "+v"(z12), "+v"(z13), "+v"(z14), "+v"(z15));

        if (tid == 0) {
            outc[it * 3 + 0] = ccx;
            outc[it * 3 + 1] = ccy;
            outc[it * 3 + 2] = ccz;
        }

        // --- AABB prune (lane k -> chunk wv+16k) ---
        bool active = false;
        if (lane < 16) {
            const float dxl = fmaxf(fmaxf(abx0 - ccx, ccx - abx1), 0.0f);
            const float dyl = fmaxf(fmaxf(aby0 - ccy, ccy - aby1), 0.0f);
            const float dzl = fmaxf(fmaxf(abz0 - ccz, ccz - abz1), 0.0f);
            const float mind2 = dxl * dxl + dyl * dyl + dzl * dzl;
            const float bound = fminf(prev_wd, cub);
            active = !(mind2 > bound * 1.001f);
        }
        const unsigned amask = (unsigned)(__ballot(active) & 0xFFFFull);

        // --- cub tighten: my chunk's update RAN iff my PAIR is active ---
        if (lane < 16 && ((amask >> (lane & 14)) & 3u)) {
            const float dxm = fmaxf(ccx - abx0, abx1 - ccx);
            const float dym = fmaxf(ccy - aby0, aby1 - ccy);
            const float dzm = fmaxf(ccz - abz0, abz1 - ccz);
            const float maxd2 = dxm * dxm + dym * dym + dzm * dzm;
            cub = fminf(cub, maxd2);
        }

        // --- UPD: pair-batched loads (512B stride -> ds_read2st64_b64), ---
        // --- unconditional min-update within an active pair (exact)     ---
        bool lredo = false;
        const int s2 = (wv << 10) | lane;   // float2 index, chunk stride 64
#define UPDP(ka, kb)                                                      \
        if (amask & (3u << (ka))) {                                       \
            const float2 pa = sxy2[s2 + ((ka) << 6)];                     \
            const float2 pb = sxy2[s2 + ((kb) << 6)];                     \
            {                                                             \
                const float dx = pa.x - ccx;                              \
                const float dy = pa.y - ccy;                              \
                const float dz = z##ka - ccz;                             \
                const float t  = (dx * dx + dy * dy) + dz * dz;           \
                const float dold =                                        \
                    __uint_as_float((unsigned)(key##ka >> 32));           \
                if (t < dold) {                                           \
                    key##ka =                                             \
                        (((unsigned long long)__float_as_uint(t)) << 32)  \
                        | (key##ka & 0xFFFFFFFFull);                      \
                    lredo |= ((ka) == bestk);                             \
                }                                                         \
            }                                                             \
            {                                                             \
                const float dx = pb.x - ccx;                              \
                const float dy = pb.y - ccy;                              \
                const float dz = z##kb - ccz;                             \
                const float t  = (dx * dx + dy * dy) + dz * dz;           \
                const float dold =                                        \
                    __uint_as_float((unsigned)(key##kb >> 32));           \
                if (t < dold) {                                           \
                    key##kb =                                             \
                        (((unsigned long long)__float_as_uint(t)) << 32)  \
                        | (key##kb & 0xFFFFFFFFull);                      \
                    lredo |= ((kb) == bestk);                             \
                }                                                         \
            }                                                             \
        }
        UPDP(0, 1)  UPDP(2, 3)   UPDP(4, 5)   UPDP(6, 7)
        UPDP(8, 9)  UPDP(10, 11) UPDP(12, 13) UPDP(14, 15)
#undef UPDP

        // --- per-lane best: recompute only when invalidated ---
        if (lredo) {
            bkey = 0ull; bestk = 0;
#define LM(k) if (key##k > bkey) { bkey = key##k; bestk = (k); }
            REPEAT16(LM)
#undef LM
        }

        // --- wave best: butterfly only when holder's best decreased ---
        const unsigned long long rb = __ballot(lredo);
        if ((rb >> holder_ln) & 1ull) {
            unsigned long long m = bkey;
            #pragma unroll
            for (int s = 32; s >= 1; s >>= 1) {
                const unsigned long long o = __shfl_xor(m, s, 64);
                m = o > m ? o : m;
            }
            holder_ln = __ffsll((long long)__ballot(bkey == m)) - 1;  // unique
            if (lane == holder_ln) {
                const float2 xy = sxy2[(wv << 10) | (bestk << 6) | lane];
                float zz = z0;
#define ZS(k) zz = (bestk == (k)) ? z##k : zz;
                REPEAT16(ZS)
#undef ZS
                hx = xy.x; hy = xy.y; hz = zz;
            }
        }

        // --- cross-wave: coords write + ONE atomicMax; ONE barrier ---
        if (lane == holder_ln) {
            wbc[(it & 1) * 16 + wv] = make_float4(hx, hy, hz, 0.0f);
            atomicMax(&slot[it & 3], bkey | (unsigned long long)wv);
        }
        if (tid == 0) slot[(it + 1) & 3] = 0ull;
        __syncthreads();

        // --- winner: broadcast slot read -> wv -> broadcast coords read ---
        // (R0 tail; the R5 readlane tail measured -98us and was reverted)
        const unsigned long long wk = slot[it & 3];
        prev_wd = __uint_as_float((unsigned)(wk >> 32));
        const int wwv = (int)(wk & 0xFull);
        const float4 wf = wbc[(it & 1) * 16 + wwv];
        ccx = wf.x; ccy = wf.y; ccz = wf.z;
    }

    // ---------- flush centroids ----------
    __syncthreads();
    float* outb = new_xyz + (size_t)b * NPOINT * 3;
    #pragma unroll
    for (int j = 0; j < 3; ++j) {
        const int idx = j * FPS_T + tid;
        outb[idx] = outc[idx];
    }
}

// ---------------------------------------------------------------------------
// K2: Ball query. One wave per query; ordered first-32 selection via ballot,
// early exit once 32 found. Exact arithmetic (contract off, rad2 = (float)0.04).
// ---------------------------------------------------------------------------
__global__ __launch_bounds__(256) void ballq_kernel(const float* __restrict__ xyz,
                                                    const float* __restrict__ new_xyz,
                                                    int* __restrict__ gidx) {
    #pragma clang fp contract(off)
    const int lane = threadIdx.x & 63;
    const int q    = blockIdx.x * 4 + (threadIdx.x >> 6);
    const int b    = q >> 10;                  // NPOINT = 1024
    const float* bx = xyz + (size_t)b * NN * 3;
    const float* nx = new_xyz + (size_t)q * 3;
    const float cx = nx[0], cy = nx[1], cz = nx[2];
    const float rad2 = 0.04f;  // f32 cast of python double 0.2**2 — NOT 0.2f*0.2f

    int* out  = gidx + (size_t)q * NSAMPLE;
    int taken = 0;
    int first = NN - 1;

    for (int chunk = 0; chunk < NN / 64 && taken < NSAMPLE; ++chunk) {
        const int   i  = chunk * 64 + lane;
        const float dx = cx - bx[i * 3 + 0];
        const float dy = cy - bx[i * 3 + 1];
        const float dz = cz - bx[i * 3 + 2];
        const float t  = dx * dx + dy * dy + dz * dz;
        const bool ok  = !(t > rad2);
        const unsigned long long m = __ballot(ok);
        const int cnt = __popcll(m);
        if (taken == 0 && cnt > 0) first = chunk * 64 + (__ffsll((long long)m) - 1);
        if (ok) {
            const int rank = taken + __popcll(m & ((1ull << lane) - 1ull));
            if (rank < NSAMPLE) out[rank] = i;
        }
        taken += cnt;
    }
    const int sat = taken < NSAMPLE ? taken : NSAMPLE;
    if (lane >= sat && lane < NSAMPLE) out[lane] = (taken > 0) ? first : (NN - 1);
}

// ---------------------------------------------------------------------------
// K3: gather feats -> LDS, MLP1 (67->64) + relu, MLP2 (64->128) + relu,
// max over the 32 samples. One 256-thread block per query. FMA allowed.
// ---------------------------------------------------------------------------
__global__ __launch_bounds__(256) void mlp_kernel(const float* __restrict__ xyz,
                                                  const float* __restrict__ points,
                                                  const float* __restrict__ w1,
                                                  const float* __restrict__ b1,
                                                  const float* __restrict__ w2,
                                                  const float* __restrict__ b2,
                                                  const float* __restrict__ new_xyz,
                                                  const int*   __restrict__ gidx,
                                                  float* __restrict__ new_points) {
    __shared__ __align__(16) float feats[32][68];
    __shared__ __align__(16) float h1s[32][64];
    __shared__ float pmax[2][128];

    const int q = blockIdx.x;
    const int b = q >> 10;
    const int t = threadIdx.x;

    {
        const int k  = t >> 3;
        const int l8 = t & 7;
        const int gi = gidx[q * 32 + k];
        const float* prow = points + ((size_t)b * NN + gi) * CC;
        const float4 v0 = *(const float4*)(prow + l8 * 8);
        const float4 v1 = *(const float4*)(prow + l8 * 8 + 4);
        *(float4*)&feats[k][4 + l8 * 8] = v0;
        *(float4*)&feats[k][8 + l8 * 8] = v1;
        if (l8 == 0) {
            const float* pr = xyz + ((size_t)b * NN + gi) * 3;
            const float* nr = new_xyz + (size_t)q * 3;
            feats[k][0] = pr[0] - nr[0];
            feats[k][1] = pr[1] - nr[1];
            feats[k][2] = pr[2] - nr[2];
        }
    }

    const int c1 = t & 63;
    float w1r[67];
    #pragma unroll
    for (int j = 0; j < 67; ++j) w1r[j] = w1[c1 * 67 + j];
    const float bb1 = b1[c1];
    __syncthreads();

    const int kg = t >> 6;
    #pragma unroll
    for (int kk = 0; kk < 8; ++kk) {
        const int kr = kg * 8 + kk;
        float acc = bb1;
        acc += feats[kr][0] * w1r[0] + feats[kr][1] * w1r[1] + feats[kr][2] * w1r[2];
        #pragma unroll
        for (int j = 0; j < 64; j += 4) {
            const float4 f = *(const float4*)&feats[kr][4 + j];
            acc += f.x * w1r[3 + j] + f.y * w1r[4 + j] + f.z * w1r[5 + j] + f.w * w1r[6 + j];
        }
        h1s[kr][c1] = fmaxf(acc, 0.0f);
    }

    const int o2 = t & 127;
    const int kh = t >> 7;
    float w2r[64];
    #pragma unroll
    for (int j = 0; j < 64; ++j) w2r[j] = w2[o2 * 64 + j];
    const float bb2 = b2[o2];
    __syncthreads();

    float mx = -INFINITY;
    #pragma unroll
    for (int kk = 0; kk < 16; ++kk) {
        const int kr = kh * 16 + kk;
        float acc = bb2;
        #pragma unroll
        for (int j = 0; j < 64; j += 4) {
            const float4 h = *(const float4*)&h1s[kr][j];
            acc += h.x * w2r[j] + h.y * w2r[j + 1] + h.z * w2r[j + 2] + h.w * w2r[j + 3];
        }
        mx = fmaxf(mx, fmaxf(acc, 0.0f));
    }
    pmax[kh][o2] = mx;
    __syncthreads();
    if (t < 128) {
        new_points[(size_t)q * 128 + t] = fmaxf(pmax[0][t], pmax[1][t]);
    }
}

// ---------------------------------------------------------------------------
extern "C" void kernel_launch(void* const* d_in, const int* in_sizes, int n_in,
                              void* d_out, int out_size, void* d_ws, size_t ws_size,
                              hipStream_t stream) {
    const float* xyz    = (const float*)d_in[0];
    const float* points = (const float*)d_in[1];
    const float* w1     = (const float*)d_in[2];
    const float* b1     = (const float*)d_in[3];
    const float* w2     = (const float*)d_in[4];
    const float* b2     = (const float*)d_in[5];

    float* out_newxyz    = (float*)d_out;
    float* out_newpoints = (float*)d_out + (size_t)BB * NPOINT * 3;
    int*    gidx    = (int*)d_ws;                                   // 512 KB
    float4* sortbuf = (float4*)((char*)d_ws + (size_t)512 * 1024);  // 1 MB

    // LDS map: sxy2 @0 (131072) | hist/outc alias @131072 (16384/12288) |
    // wbc @147456 (512) | slot @147968 (32) | wsum @148000 (64) -> 148064
    const int fps_lds = 148064;
    (void)hipFuncSetAttribute((const void*)fps_kernel,
                              hipFuncAttributeMaxDynamicSharedMemorySize,
                              fps_lds);

    fps_kernel<<<BB, FPS_T, fps_lds, stream>>>(xyz, out_newxyz, sortbuf);
    ballq_kernel<<<(BB * NPOINT) / 4, 256, 0, stream>>>(xyz, out_newxyz, gidx);
    mlp_kernel<<<BB * NPOINT, 256, 0, stream>>>(xyz, points, w1, b1, w2, b2,
                                                out_newxyz, gidx, out_newpoints);
}

// Round 7
// 1453.292 us; speedup vs baseline: 1.5263x; 1.1475x over previous
//
#include <hip/hip_runtime.h>

#define BB 4
#define NN 16384
#define CC 64
#define NPOINT 1024
#define NSAMPLE 32

#define FPS_T 1024
#define NCHUNK 256          // 64 points per chunk
#define NCELL 4096          // 16^3 Morton cells

#define REPEAT16(M) M(0) M(1) M(2) M(3) M(4) M(5) M(6) M(7) \
                    M(8) M(9) M(10) M(11) M(12) M(13) M(14) M(15)

// ---------------------------------------------------------------------------
// K1: Pruned FPS, 16 waves, event-driven reductions, atomic cross-wave
// reduce, no global ops in the iteration loop.
//  == R0 (1420us steady, VGPR=56, zero scratch) + ONE isolated change ==
//  Ledger: R5 readlane tail -98us (reverted); R6 pair-batched UPD -77us
//  (reverted) -> UPD LDS latency is NOT the dominant term. Remaining large
//  serial term: the u64 __shfl_xor butterfly = 6 stages x 2 ds_swizzle
//  (~400cy dependent LDS-crosslane latency). Event-driven gating makes it
//  rare PER WAVE, but the winner's wave fires it ~every iteration (its
//  best point's d collapses) and the block barrier syncs to the slowest
//  wave -> it is on the BLOCK critical path every iteration.
//  THIS ROUND: fast-path wave reduce via DPP (pure VALU, no LDS):
//   6x v_max_f32 dpp (row_shr:1/2/4/8, row_bcast:15/31) on the key's
//   d-word (d>=0 -> f32 order == uint order), readlane(63) + ballot ->
//   holder. Cross-lane d-ties (rare) fall back to the exact u64 butterfly
//   -> tie-break bit-exact. Everything else byte-identical to R0:
//  - Morton counting-sort: sb (global, float4 x,y,z,orig) + sxy (LDS float2).
//  - Wave wv owns chunks {wv+16k}; lane L holds u64 key##k =
//    d_bits<<32 | tb<<4 (tb = 0x3FFF-orig, globally unique) — LOOP-CARRIED.
//    z##k asm-pinned. AABB of chunk wv+16k in lane-k registers.
//  - Prune: chunk active iff mind2(AABB,c) <= min(prev_wd, cub)*1.001 where
//    cub = min over processed centroids of maxdist2(AABB,c) >= chunk max d
//    (maintained in the test itself, lane k). Exact-conservative skip.
//  - Event-driven: lane best recomputed only when its best's key decreased;
//    wave reduce only when holder lane's best decreased. Unique keys ->
//    first-original-index tie-break exact.
//  - Cross-wave: holder writes coords to wbc dbuf + ONE atomicMax of
//    (bkey|wv) into slot[it&3]; ONE barrier; broadcast slot read -> wv ->
//    broadcast coords read (R0 tail).
//  - Centroids buffered in LDS outc[], flushed after the loop.
// Bit-exact: contract(off), (dx*dx+dy*dy)+dz*dz order, min-as-cond-update.
// ---------------------------------------------------------------------------
__global__ __launch_bounds__(FPS_T) void fps_kernel(const float* __restrict__ xyz,
                                                    float* __restrict__ new_xyz,
                                                    float4* __restrict__ sorted) {
    #pragma clang fp contract(off)
    extern __shared__ char smem_raw[];
    float2* sxy  = (float2*)smem_raw;                         // 131072 B
    int*    hist = (int*)(smem_raw + 131072);                 // 16384 B (setup)
    float*  outc = (float*)(smem_raw + 131072);               // 12288 B (alias)
    float4* wbc  = (float4*)(smem_raw + 153984);              // [2][16] 512 B
    unsigned long long* slot = (unsigned long long*)(smem_raw + 154496); // [4]
    int*    wsum = (int*)(smem_raw + 154528);                 // [16]

    const int b    = blockIdx.x;
    const int tid  = threadIdx.x;
    const int lane = tid & 63;
    const int wv   = tid >> 6;                  // 0..15
    const float* bx = xyz + (size_t)b * NN * 3;
    float4* sb = sorted + (size_t)b * NN;

    // ---------- phase 0a: histogram of Morton cell codes ----------
    #pragma unroll
    for (int j = 0; j < 4; ++j) hist[j * FPS_T + tid] = 0;
    __syncthreads();

    #pragma unroll
    for (int j = 0; j < 16; ++j) {
        const int p = j * FPS_T + tid;
        const float x = bx[p * 3 + 0], y = bx[p * 3 + 1], z = bx[p * 3 + 2];
        int cx = (int)(x * 16.0f); cx = cx > 15 ? 15 : (cx < 0 ? 0 : cx);
        int cy = (int)(y * 16.0f); cy = cy > 15 ? 15 : (cy < 0 ? 0 : cy);
        int cz = (int)(z * 16.0f); cz = cz > 15 ? 15 : (cz < 0 ? 0 : cz);
        int code = 0;
        #pragma unroll
        for (int i = 0; i < 4; ++i)
            code |= (((cx >> i) & 1) << (3 * i)) |
                    (((cy >> i) & 1) << (3 * i + 1)) |
                    (((cz >> i) & 1) << (3 * i + 2));
        atomicAdd(&hist[code], 1);
    }
    __syncthreads();

    // ---------- phase 0b: exclusive scan ----------
    {
        const int h0 = hist[4 * tid + 0], h1 = hist[4 * tid + 1];
        const int h2 = hist[4 * tid + 2], h3 = hist[4 * tid + 3];
        const int s  = h0 + h1 + h2 + h3;
        int v = s;
        #pragma unroll
        for (int o = 1; o < 64; o <<= 1) {
            const int u = __shfl_up(v, o, 64);
            if (lane >= o) v += u;
        }
        if (lane == 63) wsum[wv] = v;
        __syncthreads();
        int base = 0;
        for (int w = 0; w < wv; ++w) base += wsum[w];
        const int e0 = base + v - s;
        hist[4 * tid + 0] = e0;
        hist[4 * tid + 1] = e0 + h0;
        hist[4 * tid + 2] = e0 + h0 + h1;
        hist[4 * tid + 3] = e0 + h0 + h1 + h2;
    }
    __syncthreads();

    // ---------- phase 0c: scatter to global sb AND LDS sxy ----------
    #pragma unroll
    for (int j = 0; j < 16; ++j) {
        const int p = j * FPS_T + tid;
        const float x = bx[p * 3 + 0], y = bx[p * 3 + 1], z = bx[p * 3 + 2];
        int cx = (int)(x * 16.0f); cx = cx > 15 ? 15 : (cx < 0 ? 0 : cx);
        int cy = (int)(y * 16.0f); cy = cy > 15 ? 15 : (cy < 0 ? 0 : cy);
        int cz = (int)(z * 16.0f); cz = cz > 15 ? 15 : (cz < 0 ? 0 : cz);
        int code = 0;
        #pragma unroll
        for (int i = 0; i < 4; ++i)
            code |= (((cx >> i) & 1) << (3 * i)) |
                    (((cy >> i) & 1) << (3 * i + 1)) |
                    (((cz >> i) & 1) << (3 * i + 2));
        const int slotg = atomicAdd(&hist[code], 1);
        sb[slotg]  = make_float4(x, y, z, __int_as_float(p));
        sxy[slotg] = make_float2(x, y);
    }
    __syncthreads();   // drains scatter stores before readback

    // ---------- phase 0d: per-chunk AABB + z/key preload ----------
#define DECLZ(k) float z##k; unsigned long long key##k;
    REPEAT16(DECLZ)
#undef DECLZ
    float abx0 = 0.f, aby0 = 0.f, abz0 = 0.f, abx1 = 0.f, aby1 = 0.f, abz1 = 0.f;

#define AABBPRE(k) { const int g = wv + ((k) << 4);                       \
    const float4 pt = sb[(g << 6) + lane];                                \
    z##k = pt.z;                                                          \
    key##k = (((unsigned long long)__float_as_uint(1e10f)) << 32) |       \
             ((unsigned long long)(0x3FFFu -                              \
                    (unsigned)__float_as_int(pt.w)) << 4);                \
    float mnx = pt.x, mxx = pt.x, mny = pt.y, mxy = pt.y,                 \
          mnz = pt.z, mxz = pt.z;                                         \
    _Pragma("unroll")                                                     \
    for (int m = 32; m >= 1; m >>= 1) {                                   \
        mnx = fminf(mnx, __shfl_xor(mnx, m, 64));                         \
        mxx = fmaxf(mxx, __shfl_xor(mxx, m, 64));                         \
        mny = fminf(mny, __shfl_xor(mny, m, 64));                         \
        mxy = fmaxf(mxy, __shfl_xor(mxy, m, 64));                         \
        mnz = fminf(mnz, __shfl_xor(mnz, m, 64));                         \
        mxz = fmaxf(mxz, __shfl_xor(mxz, m, 64));                         \
    }                                                                     \
    if (lane == (k)) { abx0 = mnx; abx1 = mxx; aby0 = mny; aby1 = mxy;    \
                       abz0 = mnz; abz1 = mxz; } }
    REPEAT16(AABBPRE)
#undef AABBPRE
    if (tid == 0) { slot[0] = 0ull; slot[1] = 0ull; slot[2] = 0ull; slot[3] = 0ull; }
    __syncthreads();

    // ---------- main loop ----------
    unsigned long long bkey = 0ull;   // my lane best (max over key0..15)
    int bestk = 0;
    int holder_ln = 0;                // wave-uniform
    float hx = 0.f, hy = 0.f, hz = 0.f;
    float cub = 1e10f;                // lane k: upper bound on chunk max d

    float ccx = bx[0], ccy = bx[1], ccz = bx[2];
    float prev_wd = 1e10f;

    for (int it = 0; it < NPOINT; ++it) {
        asm volatile("" : "+v"(z0), "+v"(z1), "+v"(z2),  "+v"(z3),
                          "+v"(z4), "+v"(z5), "+v"(z6),  "+v"(z7),
                          "+v"(z8), "+v"(z9), "+v"(z10), "+v"(z11),
                          "+v"(z12), "+v"(z13), "+v"(z14), "+v"(z15));

        if (tid == 0) {
            outc[it * 3 + 0] = ccx;
            outc[it * 3 + 1] = ccy;
            outc[it * 3 + 2] = ccz;
        }

        // --- AABB prune + cub maintenance (lane k -> chunk wv+16k) ---
        bool active = false;
        if (lane < 16) {
            const float dxl = fmaxf(fmaxf(abx0 - ccx, ccx - abx1), 0.0f);
            const float dyl = fmaxf(fmaxf(aby0 - ccy, ccy - aby1), 0.0f);
            const float dzl = fmaxf(fmaxf(abz0 - ccz, ccz - abz1), 0.0f);
            const float mind2 = dxl * dxl + dyl * dyl + dzl * dzl;
            const float bound = fminf(prev_wd, cub);
            active = !(mind2 > bound * 1.001f);
            if (active) {
                // chunk will be processed with this centroid: tighten cub
                const float dxm = fmaxf(ccx - abx0, abx1 - ccx);
                const float dym = fmaxf(ccy - aby0, aby1 - ccy);
                const float dzm = fmaxf(ccz - abz0, abz1 - ccz);
                const float maxd2 = dxm * dxm + dym * dym + dzm * dzm;
                cub = fminf(cub, maxd2);
            }
        }
        const unsigned amask = (unsigned)(__ballot(active) & 0xFFFFull);

        bool lredo = false;
#define UPD(k) if (amask & (1u << (k))) {                                 \
            const int g = wv + ((k) << 4);                                \
            const float2 xy = sxy[(g << 6) + lane];                       \
            const float dx = xy.x - ccx;                                  \
            const float dy = xy.y - ccy;                                  \
            const float dz = z##k - ccz;                                  \
            const float t  = (dx * dx + dy * dy) + dz * dz;               \
            const float dold = __uint_as_float((unsigned)(key##k >> 32)); \
            if (t < dold) {                                               \
                key##k = (((unsigned long long)__float_as_uint(t)) << 32) \
                         | (key##k & 0xFFFFFFFFull);                      \
                lredo |= ((k) == bestk);                                  \
            }                                                             \
        }
        if (amask & 0x000Fu) { UPD(0)  UPD(1)  UPD(2)  UPD(3)  }
        if (amask & 0x00F0u) { UPD(4)  UPD(5)  UPD(6)  UPD(7)  }
        if (amask & 0x0F00u) { UPD(8)  UPD(9)  UPD(10) UPD(11) }
        if (amask & 0xF000u) { UPD(12) UPD(13) UPD(14) UPD(15) }
#undef UPD

        // --- per-lane best: recompute only when invalidated ---
        if (lredo) {
            bkey = 0ull; bestk = 0;
#define LM(k) if (key##k > bkey) { bkey = key##k; bestk = (k); }
            REPEAT16(LM)
#undef LM
        }

        // --- wave best: reduce only when holder's best decreased ---
        const unsigned long long rb = __ballot(lredo);
        if ((rb >> holder_ln) & 1ull) {
            // FAST PATH: DPP max-reduce on the f32 d-word (pure VALU, no
            // LDS crosslane). d >= 0 -> IEEE f32 order == uint order.
            const float bdf = __uint_as_float((unsigned)(bkey >> 32));
            int xi = __float_as_int(bdf);
#define DPPMAX(ctrl) { const int t_ = __builtin_amdgcn_update_dpp(        \
                           xi, xi, (ctrl), 0xF, 0xF, false);              \
                       xi = __float_as_int(fmaxf(__int_as_float(xi),      \
                                                 __int_as_float(t_))); }
            DPPMAX(0x111)  // row_shr:1
            DPPMAX(0x112)  // row_shr:2
            DPPMAX(0x114)  // row_shr:4
            DPPMAX(0x118)  // row_shr:8
            DPPMAX(0x142)  // row_bcast:15
            DPPMAX(0x143)  // row_bcast:31  -> lane 63 holds wave max
#undef DPPMAX
            const float m32 = __int_as_float(__builtin_amdgcn_readlane(xi, 63));
            const unsigned long long cmask = __ballot(bdf == m32);
            if (__popcll(cmask) == 1) {
                holder_ln = __ffsll((long long)cmask) - 1;
            } else {
                // exact u64 butterfly fallback on cross-lane d-ties (rare;
                // unique tb -> first-original-index tie-break preserved)
                unsigned long long m = bkey;
                #pragma unroll
                for (int s = 32; s >= 1; s >>= 1) {
                    const unsigned long long o = __shfl_xor(m, s, 64);
                    m = o > m ? o : m;
                }
                holder_ln = __ffsll((long long)__ballot(bkey == m)) - 1;
            }
            if (lane == holder_ln) {
                const float2 xy = sxy[((wv + (bestk << 4)) << 6) + lane];
                float zz = z0;
#define ZS(k) zz = (bestk == (k)) ? z##k : zz;
                REPEAT16(ZS)
#undef ZS
                hx = xy.x; hy = xy.y; hz = zz;
            }
        }

        // --- cross-wave: coords write + ONE atomicMax; ONE barrier ---
        if (lane == holder_ln) {
            wbc[(it & 1) * 16 + wv] = make_float4(hx, hy, hz, 0.0f);
            atomicMax(&slot[it & 3], bkey | (unsigned long long)wv);
        }
        if (tid == 0) slot[(it + 1) & 3] = 0ull;
        __syncthreads();

        // --- winner: broadcast slot read -> wv -> broadcast coords read ---
        const unsigned long long wk = slot[it & 3];
        prev_wd = __uint_as_float((unsigned)(wk >> 32));
        const int wwv = (int)(wk & 0xFull);
        const float4 wf = wbc[(it & 1) * 16 + wwv];
        ccx = wf.x; ccy = wf.y; ccz = wf.z;
    }

    // ---------- flush centroids ----------
    __syncthreads();
    float* outb = new_xyz + (size_t)b * NPOINT * 3;
    #pragma unroll
    for (int j = 0; j < 3; ++j) {
        const int idx = j * FPS_T + tid;
        outb[idx] = outc[idx];
    }
}

// ---------------------------------------------------------------------------
// K2: Ball query. One wave per query; ordered first-32 selection via ballot,
// early exit once 32 found. Exact arithmetic (contract off, rad2 = (float)0.04).
// ---------------------------------------------------------------------------
__global__ __launch_bounds__(256) void ballq_kernel(const float* __restrict__ xyz,
                                                    const float* __restrict__ new_xyz,
                                                    int* __restrict__ gidx) {
    #pragma clang fp contract(off)
    const int lane = threadIdx.x & 63;
    const int q    = blockIdx.x * 4 + (threadIdx.x >> 6);
    const int b    = q >> 10;                  // NPOINT = 1024
    const float* bx = xyz + (size_t)b * NN * 3;
    const float* nx = new_xyz + (size_t)q * 3;
    const float cx = nx[0], cy = nx[1], cz = nx[2];
    const float rad2 = 0.04f;  // f32 cast of python double 0.2**2 — NOT 0.2f*0.2f

    int* out  = gidx + (size_t)q * NSAMPLE;
    int taken = 0;
    int first = NN - 1;

    for (int chunk = 0; chunk < NN / 64 && taken < NSAMPLE; ++chunk) {
        const int   i  = chunk * 64 + lane;
        const float dx = cx - bx[i * 3 + 0];
        const float dy = cy - bx[i * 3 + 1];
        const float dz = cz - bx[i * 3 + 2];
        const float t  = dx * dx + dy * dy + dz * dz;
        const bool ok  = !(t > rad2);
        const unsigned long long m = __ballot(ok);
        const int cnt = __popcll(m);
        if (taken == 0 && cnt > 0) first = chunk * 64 + (__ffsll((long long)m) - 1);
        if (ok) {
            const int rank = taken + __popcll(m & ((1ull << lane) - 1ull));
            if (rank < NSAMPLE) out[rank] = i;
        }
        taken += cnt;
    }
    const int sat = taken < NSAMPLE ? taken : NSAMPLE;
    if (lane >= sat && lane < NSAMPLE) out[lane] = (taken > 0) ? first : (NN - 1);
}

// ---------------------------------------------------------------------------
// K3: gather feats -> LDS, MLP1 (67->64) + relu, MLP2 (64->128) + relu,
// max over the 32 samples. One 256-thread block per query. FMA allowed.
// ---------------------------------------------------------------------------
__global__ __launch_bounds__(256) void mlp_kernel(const float* __restrict__ xyz,
                                                  const float* __restrict__ points,
                                                  const float* __restrict__ w1,
                                                  const float* __restrict__ b1,
                                                  const float* __restrict__ w2,
                                                  const float* __restrict__ b2,
                                                  const float* __restrict__ new_xyz,
                                                  const int*   __restrict__ gidx,
                                                  float* __restrict__ new_points) {
    __shared__ __align__(16) float feats[32][68];
    __shared__ __align__(16) float h1s[32][64];
    __shared__ float pmax[2][128];

    const int q = blockIdx.x;
    const int b = q >> 10;
    const int t = threadIdx.x;

    {
        const int k  = t >> 3;
        const int l8 = t & 7;
        const int gi = gidx[q * 32 + k];
        const float* prow = points + ((size_t)b * NN + gi) * CC;
        const float4 v0 = *(const float4*)(prow + l8 * 8);
        const float4 v1 = *(const float4*)(prow + l8 * 8 + 4);
        *(float4*)&feats[k][4 + l8 * 8] = v0;
        *(float4*)&feats[k][8 + l8 * 8] = v1;
        if (l8 == 0) {
            const float* pr = xyz + ((size_t)b * NN + gi) * 3;
            const float* nr = new_xyz + (size_t)q * 3;
            feats[k][0] = pr[0] - nr[0];
            feats[k][1] = pr[1] - nr[1];
            feats[k][2] = pr[2] - nr[2];
        }
    }

    const int c1 = t & 63;
    float w1r[67];
    #pragma unroll
    for (int j = 0; j < 67; ++j) w1r[j] = w1[c1 * 67 + j];
    const float bb1 = b1[c1];
    __syncthreads();

    const int kg = t >> 6;
    #pragma unroll
    for (int kk = 0; kk < 8; ++kk) {
        const int kr = kg * 8 + kk;
        float acc = bb1;
        acc += feats[kr][0] * w1r[0] + feats[kr][1] * w1r[1] + feats[kr][2] * w1r[2];
        #pragma unroll
        for (int j = 0; j < 64; j += 4) {
            const float4 f = *(const float4*)&feats[kr][4 + j];
            acc += f.x * w1r[3 + j] + f.y * w1r[4 + j] + f.z * w1r[5 + j] + f.w * w1r[6 + j];
        }
        h1s[kr][c1] = fmaxf(acc, 0.0f);
    }

    const int o2 = t & 127;
    const int kh = t >> 7;
    float w2r[64];
    #pragma unroll
    for (int j = 0; j < 64; ++j) w2r[j] = w2[o2 * 64 + j];
    const float bb2 = b2[o2];
    __syncthreads();

    float mx = -INFINITY;
    #pragma unroll
    for (int kk = 0; kk < 16; ++kk) {
        const int kr = kh * 16 + kk;
        float acc = bb2;
        #pragma unroll
        for (int j = 0; j < 64; j += 4) {
            const float4 h = *(const float4*)&h1s[kr][j];
            acc += h.x * w2r[j] + h.y * w2r[j + 1] + h.z * w2r[j + 2] + h.w * w2r[j + 3];
        }
        mx = fmaxf(mx, fmaxf(acc, 0.0f));
    }
    pmax[kh][o2] = mx;
    __syncthreads();
    if (t < 128) {
        new_points[(size_t)q * 128 + t] = fmaxf(pmax[0][t], pmax[1][t]);
    }
}

// ---------------------------------------------------------------------------
extern "C" void kernel_launch(void* const* d_in, const int* in_sizes, int n_in,
                              void* d_out, int out_size, void* d_ws, size_t ws_size,
                              hipStream_t stream) {
    const float* xyz    = (const float*)d_in[0];
    const float* points = (const float*)d_in[1];
    const float* w1     = (const float*)d_in[2];
    const float* b1     = (const float*)d_in[3];
    const float* w2     = (const float*)d_in[4];
    const float* b2     = (const float*)d_in[5];

    float* out_newxyz    = (float*)d_out;
    float* out_newpoints = (float*)d_out + (size_t)BB * NPOINT * 3;
    int*    gidx    = (int*)d_ws;                                   // 512 KB
    float4* sortbuf = (float4*)((char*)d_ws + (size_t)512 * 1024);  // 1 MB

    // LDS map: sxy 131072 | hist/outc alias @131072 (16384) | wbc @153984
    // (512) | slot @154496 (32) | wsum @154528 (64)
    const int fps_lds = 154816;
    (void)hipFuncSetAttribute((const void*)fps_kernel,
                              hipFuncAttributeMaxDynamicSharedMemorySize,
                              fps_lds);

    fps_kernel<<<BB, FPS_T, fps_lds, stream>>>(xyz, out_newxyz, sortbuf);
    ballq_kernel<<<(BB * NPOINT) / 4, 256, 0, stream>>>(xyz, out_newxyz, gidx);
    mlp_kernel<<<BB * NPOINT, 256, 0, stream>>>(xyz, points, w1, b1, w2, b2,
                                                out_newxyz, gidx, out_newpoints);
}